// Round 9
// baseline (301.767 us; speedup 1.0000x reference)
//
#include <hip/hip_runtime.h>

typedef __bf16 bf16x8 __attribute__((ext_vector_type(8)));
typedef float f32x4 __attribute__((ext_vector_type(4)));
typedef float f32x16 __attribute__((ext_vector_type(16)));
typedef _Float16 h4 __attribute__((ext_vector_type(4)));
typedef unsigned short u16;

#define ASYNC16(gp, lp) __builtin_amdgcn_global_load_lds( \
    (__attribute__((address_space(1))) void*)(gp),        \
    (__attribute__((address_space(3))) void*)(lp), 16, 0, 0)

// ---------------- helpers ----------------
static __device__ __forceinline__ u16 f2bf(float f) {
    union { float f; unsigned u; } v; v.f = f;
    unsigned r = v.u + 0x7FFFu + ((v.u >> 16) & 1u);   // RNE
    return (u16)(r >> 16);
}
static __device__ __forceinline__ u16 f2h(float f) {
    _Float16 h = (_Float16)f;
    union { _Float16 h; u16 u; } c; c.h = h;
    return c.u;
}

#define QSCALE 0.18033688011112042f  /* 0.125 * log2(e) */

// ---------------- fused weight transpose+convert (4 weights, 1 launch) -------
// out[n*K + k] = bf16(in[k*N + n]); block (32,8)
__global__ void prep_weights(const float* __restrict__ W0, u16* __restrict__ O0,
                             const float* __restrict__ W1, u16* __restrict__ O1,
                             const float* __restrict__ W2, u16* __restrict__ O2,
                             const float* __restrict__ W3, u16* __restrict__ O3) {
    __shared__ float tile[32][33];
    int id = blockIdx.x;
    const float* in; u16* out; int K, N, bx, by;
    if (id < 3072)      { in = W0; out = O0; K = 1024; N = 3072; bx = id % 96; by = id / 96; }
    else if (id < 4096) { id -= 3072; in = W1; out = O1; K = 1024; N = 1024; bx = id % 32; by = id / 32; }
    else if (id < 6144) { id -= 4096; in = W2; out = O2; K = 1024; N = 2048; bx = id % 64; by = id / 64; }
    else                { id -= 6144; in = W3; out = O3; K = 2048; N = 1024; bx = id % 32; by = id / 32; }
    int n0 = bx * 32, k0 = by * 32;
    int tx = threadIdx.x, ty = threadIdx.y;
    for (int i = 0; i < 4; i++)
        tile[ty + 8 * i][tx] = in[(size_t)(k0 + ty + 8 * i) * N + n0 + tx];
    __syncthreads();
    for (int i = 0; i < 4; i++)
        out[(size_t)(n0 + ty + 8 * i) * K + k0 + tx] = f2bf(tile[tx][ty + 8 * i]);
}

__global__ void convert_bf16(const float* __restrict__ in, u16* __restrict__ out) {
    size_t i = ((size_t)blockIdx.x * 256 + threadIdx.x) * 4;
    float4 v = *(const float4*)&in[i];
    u16 o0 = f2bf(v.x), o1 = f2bf(v.y), o2 = f2bf(v.z), o3 = f2bf(v.w);
    ushort4 o; o.x = o0; o.y = o1; o.z = o2; o.w = o3;
    *(ushort4*)&out[i] = o;
}

// V [bh][t][d] -> VT [bh][d][t]   grid(32, 32) block(64,8)   (u16 passthrough)
__global__ void vtrans_kernel(const u16* __restrict__ Vp, u16* __restrict__ VT) {
    __shared__ u16 tile[64 * 66];
    const int bh = blockIdx.y, t0 = blockIdx.x * 64;
    const int tx = threadIdx.x, ty = threadIdx.y;
    const u16* src = Vp + (size_t)bh * 2048 * 64;
    u16* dst = VT + (size_t)bh * 64 * 2048;
    for (int i = 0; i < 8; i++)
        tile[(ty + 8 * i) * 66 + tx] = src[(size_t)(t0 + ty + 8 * i) * 64 + tx];
    __syncthreads();
    for (int i = 0; i < 8; i++) {
        int d = ty + 8 * i;
        dst[(size_t)d * 2048 + t0 + tx] = tile[tx * 66 + d];
    }
}

// ---------------- GEMM 128x128, single-barrier double-buffered pipeline ----------
// EPI 0: scatter to Q/K (bf16) + V (f16) [B,H,T,D]; Q scaled by QSCALE
// EPI 1: fp32 out = acc + bias + resid[m*N+n]
// EPI 2: bf16 out = relu(acc + bias)
template <int EPI>
__global__ __launch_bounds__(256) void gemm_kernel(
    const u16* __restrict__ A, const u16* __restrict__ BT,
    const float* __restrict__ bias, void* __restrict__ out0,
    const float* __restrict__ resid, int M, int N, int K,
    u16* __restrict__ q_out, u16* __restrict__ k_out, u16* __restrict__ v_out)
{
    __shared__ __align__(16) u16 As[2][128 * 32];
    __shared__ __align__(16) u16 Bs[2][128 * 32];
    const int tid = threadIdx.x;
    const int wave = tid >> 6, lane = tid & 63;
    const int quad = lane >> 4, l16 = lane & 15;
    const int m0 = blockIdx.y * 128, n0 = blockIdx.x * 128;
    const int wm = (wave >> 1) * 64, wn = (wave & 1) * 64;
    const int sr = tid >> 2, sc = (tid & 3) * 8;

    f32x4 acc[4][4] = {};

#define GISSUE(k0v, bb) do {                                                         \
        ASYNC16(&A[(size_t)(m0 + sr) * K + (k0v) + sc],       &As[bb][sr * 32 + sc]);        \
        ASYNC16(&A[(size_t)(m0 + sr + 64) * K + (k0v) + sc],  &As[bb][(sr + 64) * 32 + sc]); \
        ASYNC16(&BT[(size_t)(n0 + sr) * K + (k0v) + sc],      &Bs[bb][sr * 32 + sc]);        \
        ASYNC16(&BT[(size_t)(n0 + sr + 64) * K + (k0v) + sc], &Bs[bb][(sr + 64) * 32 + sc]); \
    } while (0)

    const int nk = K >> 5;
    GISSUE(0, 0);
    for (int it = 0; it < nk; it++) {
        __syncthreads();
        if (it + 1 < nk) GISSUE((it + 1) * 32, (it + 1) & 1);
        const u16* Ab = As[it & 1];
        const u16* Bb = Bs[it & 1];
        bf16x8 af[4], bfr[4];
        for (int i = 0; i < 4; i++) {
            af[i]  = *(const bf16x8*)&Ab[(wm + i * 16 + l16) * 32 + quad * 8];
            bfr[i] = *(const bf16x8*)&Bb[(wn + i * 16 + l16) * 32 + quad * 8];
        }
        for (int i = 0; i < 4; i++)
            for (int j = 0; j < 4; j++)
                acc[i][j] = __builtin_amdgcn_mfma_f32_16x16x32_bf16(af[i], bfr[j], acc[i][j], 0, 0, 0);
    }
#undef GISSUE

    for (int i = 0; i < 4; i++) {
        int mbase = m0 + wm + i * 16 + quad * 4;
        for (int j = 0; j < 4; j++) {
            int n = n0 + wn + j * 16 + l16;
            float bv = bias[n];
            for (int r = 0; r < 4; r++) {
                int m = mbase + r;
                float v = acc[i][j][r] + bv;
                if (EPI == 0) {
                    int s = n >> 10, rr = n & 1023, h = rr >> 6, d = rr & 63;
                    int b = m >> 11, t = m & 2047;
                    if (s == 0) v *= QSCALE;
                    u16* dst = (s == 0) ? q_out : (s == 1) ? k_out : v_out;
                    u16 bits = (s == 2) ? f2h(v) : f2bf(v);
                    dst[((size_t)((b * 16 + h) * 2048 + t)) * 64 + d] = bits;
                } else if (EPI == 1) {
                    ((float*)out0)[(size_t)m * N + n] = v + resid[(size_t)m * N + n];
                } else {
                    ((u16*)out0)[(size_t)m * N + n] = f2bf(fmaxf(v, 0.f));
                }
            }
        }
    }
}

// ---------------- GEMM 64x128 (N=1024 GEMMs: 512 blocks => 2/CU) -----------
__global__ __launch_bounds__(256) void gemm64_kernel(
    const u16* __restrict__ A, const u16* __restrict__ BT,
    const float* __restrict__ bias, float* __restrict__ out0,
    const float* __restrict__ resid, int M, int N, int K)
{
    __shared__ __align__(16) u16 As[2][64 * 32];
    __shared__ __align__(16) u16 Bs[2][128 * 32];
    const int tid = threadIdx.x;
    const int wave = tid >> 6, lane = tid & 63;
    const int quad = lane >> 4, l16 = lane & 15;
    const int m0 = blockIdx.y * 64, n0 = blockIdx.x * 128;
    const int wn = wave * 32;
    const int sr = tid >> 2, sc = (tid & 3) * 8;

    f32x4 acc[4][2] = {};

#define GISSUE(k0v, bb) do {                                                         \
        ASYNC16(&A[(size_t)(m0 + sr) * K + (k0v) + sc],       &As[bb][sr * 32 + sc]);        \
        ASYNC16(&BT[(size_t)(n0 + sr) * K + (k0v) + sc],      &Bs[bb][sr * 32 + sc]);        \
        ASYNC16(&BT[(size_t)(n0 + sr + 64) * K + (k0v) + sc], &Bs[bb][(sr + 64) * 32 + sc]); \
    } while (0)

    const int nk = K >> 5;
    GISSUE(0, 0);
    for (int it = 0; it < nk; it++) {
        __syncthreads();
        if (it + 1 < nk) GISSUE((it + 1) * 32, (it + 1) & 1);
        const u16* Ab = As[it & 1];
        const u16* Bb = Bs[it & 1];
        bf16x8 af[4], bfr[2];
        for (int i = 0; i < 4; i++)
            af[i] = *(const bf16x8*)&Ab[(i * 16 + l16) * 32 + quad * 8];
        for (int j = 0; j < 2; j++)
            bfr[j] = *(const bf16x8*)&Bb[(wn + j * 16 + l16) * 32 + quad * 8];
        for (int i = 0; i < 4; i++)
            for (int j = 0; j < 2; j++)
                acc[i][j] = __builtin_amdgcn_mfma_f32_16x16x32_bf16(af[i], bfr[j], acc[i][j], 0, 0, 0);
    }
#undef GISSUE

    for (int i = 0; i < 4; i++) {
        int mbase = m0 + i * 16 + quad * 4;
        for (int j = 0; j < 2; j++) {
            int n = n0 + wn + j * 16 + l16;
            float bv = bias[n];
            for (int r = 0; r < 4; r++) {
                int m = mbase + r;
                out0[(size_t)m * N + n] = acc[i][j][r] + bv + resid[(size_t)m * N + n];
            }
        }
    }
}

// ---------------- flash attention v8: 32x32 MFMAs, in-register P ----------------
// Block = 128 threads (2 waves x 32 q-rows), grid = 32 qtiles * 32 bh = 1024.
// S^T = K*Q^T via mfma_32x32x16_bf16 (A=K b128 from LDS, B=Q in regs).
// C-layout row t=(reg&3)+8*(reg>>2)+4*(lane>>5) maps IN-LANE onto the
// mfma_32x32x8f16 A-slots (k=(lane>>5)*4+j, reg r=4*tc+j): P never touches LDS.
// V f16 in padded LDS [64][68] (b64 reads), plain-staged; K via global_load_lds.
__global__ __launch_bounds__(128) void attn_kernel(
    const u16* __restrict__ Qp, const u16* __restrict__ Kp,
    const u16* __restrict__ VTg, u16* __restrict__ Hb)
{
    __shared__ __align__(16) u16 Ks[2][2][64][32];   // [buf][d-panel][t][d]  bf16
    __shared__ __align__(16) u16 Vs[2][64][68];      // [buf][d][t+pad]       f16
    const int tid = threadIdx.x;
    const int wv = tid >> 6, lane = tid & 63;
    const int l32 = lane & 31, hf = lane >> 5;
    const int bh = ((blockIdx.x & 7) << 2) | ((blockIdx.x >> 3) & 3);
    const int qt = 31 - (blockIdx.x >> 5);           // heavy tiles first
    const int nk = qt + 1;
    const size_t kbase = (size_t)bh * 2048 * 64;
    const u16* Vt = VTg + (size_t)bh * 64 * 2048;

    const int qrow = qt * 64 + wv * 32;
    const int qg = qrow + l32;
    bf16x8 qB[4];
    for (int c = 0; c < 4; c++)
        qB[c] = *(const bf16x8*)&Qp[kbase + (size_t)(qrow + l32) * 64 + c * 16 + 8 * hf];

    f32x16 o[2] = {};
    float lsum = 0.f;

#define AISSUE(k0v, bb) do {                                                                   \
        for (int p = 0; p < 2; p++)                                                            \
            for (int i = 0; i < 2; i++)                                                        \
                ASYNC16(&Kp[kbase + (size_t)((k0v) + i * 32 + (tid >> 2)) * 64 + p * 32 + (tid & 3) * 8], \
                        &Ks[bb][p][i * 32 + (tid >> 2)][(tid & 3) * 8]);                       \
        for (int c = 0; c < 4; c++) {                                                          \
            uint4 gv = *(const uint4*)&Vt[(size_t)(tid >> 1) * 2048 + (k0v) + (tid & 1) * 32 + c * 8]; \
            *(uint2*)&Vs[bb][tid >> 1][(tid & 1) * 32 + c * 8]     = make_uint2(gv.x, gv.y);   \
            *(uint2*)&Vs[bb][tid >> 1][(tid & 1) * 32 + c * 8 + 4] = make_uint2(gv.z, gv.w);   \
        }                                                                                      \
    } while (0)

    AISSUE(0, 0);
    for (int g = 0; g < nk; g++) {
        __syncthreads();   // drains DMA/stores issued at g-1; guards buffer reuse
        if (g + 1 < nk) AISSUE((g + 1) * 64, (g + 1) & 1);
        const int cur = g & 1;
        const int k0 = g * 64;
        const bool diag = (g == nk - 1);

        for (int th = 0; th < 2; th++) {
            if (diag && wv == 0 && th == 1) break;   // wave-uniform: fully-masked half
            f32x16 s = {};
            for (int c = 0; c < 4; c++) {
                const int dcol = c * 16 + 8 * hf;
                const bf16x8 af = *(const bf16x8*)&Ks[cur][dcol >> 5][th * 32 + l32][dcol & 31];
                s = __builtin_amdgcn_mfma_f32_32x32x16_bf16(af, qB[c], s, 0, 0, 0);
            }
            _Float16 ph[16];
            if (diag) {
                for (int r = 0; r < 16; r++) {
                    int tg = k0 + th * 32 + (r & 3) + 8 * (r >> 2) + 4 * hf;
                    float p = (tg <= qg) ? __builtin_amdgcn_exp2f(s[r]) : 0.f;
                    lsum += p; ph[r] = (_Float16)p;
                }
            } else {
                for (int r = 0; r < 16; r++) {
                    float p = __builtin_amdgcn_exp2f(s[r]);
                    lsum += p; ph[r] = (_Float16)p;
                }
            }
            for (int tc = 0; tc < 4; tc++) {
                h4 pa = { ph[4 * tc], ph[4 * tc + 1], ph[4 * tc + 2], ph[4 * tc + 3] };
                const int tcol = th * 32 + tc * 8 + 4 * hf;
                for (int dc = 0; dc < 2; dc++) {
                    h4 vb = *(const h4*)&Vs[cur][dc * 32 + l32][tcol];
                    o[dc] = __builtin_amdgcn_mfma_f32_32x32x8f16(pa, vb, o[dc], 0, 0, 0);
                }
            }
        }
    }
#undef AISSUE

    // full row-sum: this lane covered half the t-pattern for q=l32; partner (^32) rest
    lsum += __shfl_xor(lsum, 32, 64);
    float rinv = 1.f / lsum;
    float rq[16];
    for (int r = 0; r < 16; r++)
        rq[r] = __shfl(rinv, (r & 3) + 8 * (r >> 2) + 4 * hf, 64);

    const int b = bh >> 4, hd = bh & 15;
    for (int dc = 0; dc < 2; dc++)
        for (int r = 0; r < 16; r++) {
            int t = qrow + (r & 3) + 8 * (r >> 2) + 4 * hf;
            Hb[((size_t)(b * 2048 + t)) * 1024 + hd * 64 + dc * 32 + l32] = f2bf(o[dc][r] * rq[r]);
        }
}

// ---------------- layernorm (row = block), optional bf16 copy ----------------
__global__ __launch_bounds__(256) void ln_kernel(
    float* __restrict__ y, const float* __restrict__ g, const float* __restrict__ be,
    u16* __restrict__ bf_out)
{
    __shared__ float red[8];
    const int row = blockIdx.x, tid = threadIdx.x;
    float4 v = *(const float4*)&y[(size_t)row * 1024 + tid * 4];
    float sum = v.x + v.y + v.z + v.w;
    float sq  = v.x * v.x + v.y * v.y + v.z * v.z + v.w * v.w;
    for (int off = 1; off < 64; off <<= 1) {
        sum += __shfl_xor(sum, off, 64);
        sq  += __shfl_xor(sq,  off, 64);
    }
    int wave = tid >> 6;
    if ((tid & 63) == 0) { red[wave * 2] = sum; red[wave * 2 + 1] = sq; }
    __syncthreads();
    sum = red[0] + red[2] + red[4] + red[6];
    sq  = red[1] + red[3] + red[5] + red[7];
    float mu = sum * (1.f / 1024.f);
    float var = sq * (1.f / 1024.f) - mu * mu;
    float rstd = rsqrtf(var + 1e-5f);
    float4 gv = *(const float4*)&g[tid * 4];
    float4 bv = *(const float4*)&be[tid * 4];
    float4 ov;
    ov.x = (v.x - mu) * rstd * gv.x + bv.x;
    ov.y = (v.y - mu) * rstd * gv.y + bv.y;
    ov.z = (v.z - mu) * rstd * gv.z + bv.z;
    ov.w = (v.w - mu) * rstd * gv.w + bv.w;
    *(float4*)&y[(size_t)row * 1024 + tid * 4] = ov;
    if (bf_out) {
        ushort4 ob;
        ob.x = f2bf(ov.x); ob.y = f2bf(ov.y); ob.z = f2bf(ov.z); ob.w = f2bf(ov.w);
        *(ushort4*)&bf_out[(size_t)row * 1024 + tid * 4] = ob;
    }
}

// ---------------- launch ----------------
extern "C" void kernel_launch(void* const* d_in, const int* in_sizes, int n_in,
                              void* d_out, int out_size, void* d_ws, size_t ws_size,
                              hipStream_t stream)
{
    const float* x     = (const float*)d_in[0];
    const float* Wqkv  = (const float*)d_in[1];
    const float* bqkv  = (const float*)d_in[2];
    const float* Wout  = (const float*)d_in[3];
    const float* bout  = (const float*)d_in[4];
    const float* g1    = (const float*)d_in[5];
    const float* be1   = (const float*)d_in[6];
    const float* Wff1  = (const float*)d_in[7];
    const float* bff1  = (const float*)d_in[8];
    const float* Wff2  = (const float*)d_in[9];
    const float* bff2  = (const float*)d_in[10];
    const float* g2    = (const float*)d_in[11];
    const float* be2   = (const float*)d_in[12];
    float* out = (float*)d_out;

    char* wsb = (char*)d_ws;
    u16* WqkvT = (u16*)(wsb + 0);                   //  6 MB [3072,1024]
    u16* WoutT = (u16*)(wsb + 6291456);             //  2 MB [1024,1024]
    u16* Wff1T = (u16*)(wsb + 8388608);             //  4 MB [2048,1024]
    u16* Wff2T = (u16*)(wsb + 12582912);            //  4 MB [1024,2048]
    u16* xb    = (u16*)(wsb + 16777216);            //  8 MB [4096,1024]; reused as VT
    u16* Qp    = (u16*)(wsb + 25165824);            //  8 MB [B,H,T,D] bf16
    u16* Kp    = (u16*)(wsb + 33554432);            //  8 MB bf16
    u16* Vp    = (u16*)(wsb + 41943040);            //  8 MB f16
    u16* Hb    = (u16*)(wsb + 50331648);            //  8 MB [4096,1024] bf16
    u16* x1b   = (u16*)(wsb + 58720256);            //  8 MB [4096,1024] bf16
    u16* ff1b  = (u16*)(wsb + 67108864);            // 16 MB [4096,2048] bf16
    float* y1  = (float*)(wsb + 83886080);          // 16 MB fp32 [4096,1024]
    u16* VTg   = xb;                                // V^T f16 [bh][d][t]

    // fused weight prep (4 transposes in 1 launch) + x convert
    hipLaunchKernelGGL(prep_weights, dim3(8192), dim3(32, 8), 0, stream,
                       Wqkv, WqkvT, Wout, WoutT, Wff1, Wff1T, Wff2, Wff2T);
    hipLaunchKernelGGL(convert_bf16, dim3(4096), dim3(256), 0, stream, x, xb);

    // QKV projection (Q pre-scaled by 0.125*log2e; V stored f16)
    hipLaunchKernelGGL((gemm_kernel<0>), dim3(24, 32), dim3(256), 0, stream,
                       xb, WqkvT, bqkv, nullptr, nullptr, 4096, 3072, 1024, Qp, Kp, Vp);
    // V transpose (f16 passthrough; overwrites xb — dead now)
    hipLaunchKernelGGL(vtrans_kernel, dim3(32, 32), dim3(64, 8), 0, stream, Vp, VTg);
    // attention
    hipLaunchKernelGGL(attn_kernel, dim3(1024), dim3(128), 0, stream, Qp, Kp, VTg, Hb);
    // out projection + residual (x) -> y1 fp32
    hipLaunchKernelGGL(gemm64_kernel, dim3(8, 64), dim3(256), 0, stream,
                       Hb, WoutT, bout, y1, x, 4096, 1024, 1024);
    // LN1 in-place on y1, emit bf16 x1b
    hipLaunchKernelGGL(ln_kernel, dim3(4096), dim3(256), 0, stream, y1, g1, be1, x1b);
    // FF1 + relu -> ff1b bf16
    hipLaunchKernelGGL((gemm_kernel<2>), dim3(16, 32), dim3(256), 0, stream,
                       x1b, Wff1T, bff1, (void*)ff1b, nullptr, 4096, 2048, 1024,
                       (u16*)nullptr, (u16*)nullptr, (u16*)nullptr);
    // FF2 + residual (y1 = x1 fp32) -> d_out fp32
    hipLaunchKernelGGL(gemm64_kernel, dim3(8, 64), dim3(256), 0, stream,
                       ff1b, Wff2T, bff2, out, y1, 4096, 1024, 2048);
    // LN2 in-place on d_out
    hipLaunchKernelGGL(ln_kernel, dim3(4096), dim3(256), 0, stream, out, g2, be2, (u16*)nullptr);
}

// Round 10
// 292.924 us; speedup vs baseline: 1.0302x; 1.0302x over previous
//
#include <hip/hip_runtime.h>

typedef __bf16 bf16x8 __attribute__((ext_vector_type(8)));
typedef float f32x4 __attribute__((ext_vector_type(4)));
typedef unsigned short u16;

#define ASYNC16(gp, lp) __builtin_amdgcn_global_load_lds( \
    (__attribute__((address_space(1))) void*)(gp),        \
    (__attribute__((address_space(3))) void*)(lp), 16, 0, 0)

// ---------------- helpers ----------------
static __device__ __forceinline__ u16 f2bf(float f) {
    union { float f; unsigned u; } v; v.f = f;
    unsigned r = v.u + 0x7FFFu + ((v.u >> 16) & 1u);   // RNE
    return (u16)(r >> 16);
}

#define QSCALE 0.18033688011112042f  /* 0.125 * log2(e) */

// ---------------- fused weight transpose+convert (4 weights, 1 launch) -------
__global__ void prep_weights(const float* __restrict__ W0, u16* __restrict__ O0,
                             const float* __restrict__ W1, u16* __restrict__ O1,
                             const float* __restrict__ W2, u16* __restrict__ O2,
                             const float* __restrict__ W3, u16* __restrict__ O3) {
    __shared__ float tile[32][33];
    int id = blockIdx.x;
    const float* in; u16* out; int K, N, bx, by;
    if (id < 3072)      { in = W0; out = O0; K = 1024; N = 3072; bx = id % 96; by = id / 96; }
    else if (id < 4096) { id -= 3072; in = W1; out = O1; K = 1024; N = 1024; bx = id % 32; by = id / 32; }
    else if (id < 6144) { id -= 4096; in = W2; out = O2; K = 1024; N = 2048; bx = id % 64; by = id / 64; }
    else                { id -= 6144; in = W3; out = O3; K = 2048; N = 1024; bx = id % 32; by = id / 32; }
    int n0 = bx * 32, k0 = by * 32;
    int tx = threadIdx.x, ty = threadIdx.y;
    for (int i = 0; i < 4; i++)
        tile[ty + 8 * i][tx] = in[(size_t)(k0 + ty + 8 * i) * N + n0 + tx];
    __syncthreads();
    for (int i = 0; i < 4; i++)
        out[(size_t)(n0 + ty + 8 * i) * K + k0 + tx] = f2bf(tile[tx][ty + 8 * i]);
}

__global__ void convert_bf16(const float* __restrict__ in, u16* __restrict__ out) {
    size_t i = ((size_t)blockIdx.x * 256 + threadIdx.x) * 4;
    float4 v = *(const float4*)&in[i];
    u16 o0 = f2bf(v.x), o1 = f2bf(v.y), o2 = f2bf(v.z), o3 = f2bf(v.w);
    ushort4 o; o.x = o0; o.y = o1; o.z = o2; o.w = o3;
    *(ushort4*)&out[i] = o;
}

// V [bh][t][d] -> VT [bh][d][t]   grid(32, 32) block(64,8)
__global__ void vtrans_kernel(const u16* __restrict__ Vp, u16* __restrict__ VT) {
    __shared__ u16 tile[64 * 66];
    const int bh = blockIdx.y, t0 = blockIdx.x * 64;
    const int tx = threadIdx.x, ty = threadIdx.y;
    const u16* src = Vp + (size_t)bh * 2048 * 64;
    u16* dst = VT + (size_t)bh * 64 * 2048;
    for (int i = 0; i < 8; i++)
        tile[(ty + 8 * i) * 66 + tx] = src[(size_t)(t0 + ty + 8 * i) * 64 + tx];
    __syncthreads();
    for (int i = 0; i < 8; i++) {
        int d = ty + 8 * i;
        dst[(size_t)d * 2048 + t0 + tx] = tile[tx * 66 + d];
    }
}

// ---------------- GEMM 128x128, single-barrier double-buffered pipeline ----------
// EPI 0: scatter to Q/K/V [B,H,T,D] bf16 (N=3072); Q scaled by QSCALE
template <int EPI>
__global__ __launch_bounds__(256) void gemm_kernel(
    const u16* __restrict__ A, const u16* __restrict__ BT,
    const float* __restrict__ bias, void* __restrict__ out0,
    const float* __restrict__ resid, int M, int N, int K,
    u16* __restrict__ q_out, u16* __restrict__ k_out, u16* __restrict__ v_out)
{
    __shared__ __align__(16) u16 As[2][128 * 32];
    __shared__ __align__(16) u16 Bs[2][128 * 32];
    const int tid = threadIdx.x;
    const int wave = tid >> 6, lane = tid & 63;
    const int quad = lane >> 4, l16 = lane & 15;
    const int m0 = blockIdx.y * 128, n0 = blockIdx.x * 128;
    const int wm = (wave >> 1) * 64, wn = (wave & 1) * 64;
    const int sr = tid >> 2, sc = (tid & 3) * 8;

    f32x4 acc[4][4] = {};

#define GISSUE(k0v, bb) do {                                                         \
        ASYNC16(&A[(size_t)(m0 + sr) * K + (k0v) + sc],       &As[bb][sr * 32 + sc]);        \
        ASYNC16(&A[(size_t)(m0 + sr + 64) * K + (k0v) + sc],  &As[bb][(sr + 64) * 32 + sc]); \
        ASYNC16(&BT[(size_t)(n0 + sr) * K + (k0v) + sc],      &Bs[bb][sr * 32 + sc]);        \
        ASYNC16(&BT[(size_t)(n0 + sr + 64) * K + (k0v) + sc], &Bs[bb][(sr + 64) * 32 + sc]); \
    } while (0)

    const int nk = K >> 5;
    GISSUE(0, 0);
    for (int it = 0; it < nk; it++) {
        __syncthreads();
        if (it + 1 < nk) GISSUE((it + 1) * 32, (it + 1) & 1);
        const u16* Ab = As[it & 1];
        const u16* Bb = Bs[it & 1];
        bf16x8 af[4], bfr[4];
        for (int i = 0; i < 4; i++) {
            af[i]  = *(const bf16x8*)&Ab[(wm + i * 16 + l16) * 32 + quad * 8];
            bfr[i] = *(const bf16x8*)&Bb[(wn + i * 16 + l16) * 32 + quad * 8];
        }
        for (int i = 0; i < 4; i++)
            for (int j = 0; j < 4; j++)
                acc[i][j] = __builtin_amdgcn_mfma_f32_16x16x32_bf16(af[i], bfr[j], acc[i][j], 0, 0, 0);
    }
#undef GISSUE

    for (int i = 0; i < 4; i++) {
        int mbase = m0 + wm + i * 16 + quad * 4;
        for (int j = 0; j < 4; j++) {
            int n = n0 + wn + j * 16 + l16;
            float bv = bias[n];
            for (int r = 0; r < 4; r++) {
                int m = mbase + r;
                float v = acc[i][j][r] + bv;
                if (EPI == 0) {
                    int s = n >> 10, rr = n & 1023, h = rr >> 6, d = rr & 63;
                    int b = m >> 11, t = m & 2047;
                    if (s == 0) v *= QSCALE;
                    u16* dst = (s == 0) ? q_out : (s == 1) ? k_out : v_out;
                    dst[((size_t)((b * 16 + h) * 2048 + t)) * 64 + d] = f2bf(v);
                } else if (EPI == 1) {
                    ((float*)out0)[(size_t)m * N + n] = v + resid[(size_t)m * N + n];
                } else {
                    ((u16*)out0)[(size_t)m * N + n] = f2bf(fmaxf(v, 0.f));
                }
            }
        }
    }
}

// ---------------- GEMM 64x128 (24 KB LDS => 4 blocks/CU at grid>=1024) -------
// EPI 1: fp32 out = acc + bias + resid ; EPI 2: bf16 out = relu(acc + bias)
template <int EPI>
__global__ __launch_bounds__(256) void gemm64_kernel(
    const u16* __restrict__ A, const u16* __restrict__ BT,
    const float* __restrict__ bias, void* __restrict__ out0,
    const float* __restrict__ resid, int M, int N, int K)
{
    __shared__ __align__(16) u16 As[2][64 * 32];
    __shared__ __align__(16) u16 Bs[2][128 * 32];
    const int tid = threadIdx.x;
    const int wave = tid >> 6, lane = tid & 63;
    const int quad = lane >> 4, l16 = lane & 15;
    const int m0 = blockIdx.y * 64, n0 = blockIdx.x * 128;
    const int wn = wave * 32;
    const int sr = tid >> 2, sc = (tid & 3) * 8;

    f32x4 acc[4][2] = {};

#define GISSUE(k0v, bb) do {                                                         \
        ASYNC16(&A[(size_t)(m0 + sr) * K + (k0v) + sc],       &As[bb][sr * 32 + sc]);        \
        ASYNC16(&BT[(size_t)(n0 + sr) * K + (k0v) + sc],      &Bs[bb][sr * 32 + sc]);        \
        ASYNC16(&BT[(size_t)(n0 + sr + 64) * K + (k0v) + sc], &Bs[bb][(sr + 64) * 32 + sc]); \
    } while (0)

    const int nk = K >> 5;
    GISSUE(0, 0);
    for (int it = 0; it < nk; it++) {
        __syncthreads();
        if (it + 1 < nk) GISSUE((it + 1) * 32, (it + 1) & 1);
        const u16* Ab = As[it & 1];
        const u16* Bb = Bs[it & 1];
        bf16x8 af[4], bfr[2];
        for (int i = 0; i < 4; i++)
            af[i] = *(const bf16x8*)&Ab[(i * 16 + l16) * 32 + quad * 8];
        for (int j = 0; j < 2; j++)
            bfr[j] = *(const bf16x8*)&Bb[(wn + j * 16 + l16) * 32 + quad * 8];
        for (int i = 0; i < 4; i++)
            for (int j = 0; j < 2; j++)
                acc[i][j] = __builtin_amdgcn_mfma_f32_16x16x32_bf16(af[i], bfr[j], acc[i][j], 0, 0, 0);
    }
#undef GISSUE

    for (int i = 0; i < 4; i++) {
        int mbase = m0 + i * 16 + quad * 4;
        for (int j = 0; j < 2; j++) {
            int n = n0 + wn + j * 16 + l16;
            float bv = bias[n];
            for (int r = 0; r < 4; r++) {
                int m = mbase + r;
                float v = acc[i][j][r] + bv;
                if (EPI == 1)
                    ((float*)out0)[(size_t)m * N + n] = v + resid[(size_t)m * N + n];
                else
                    ((u16*)out0)[(size_t)m * N + n] = f2bf(fmaxf(v, 0.f));
            }
        }
    }
}

// ---------------- flash attention v7 (proven 43.4 us) ----------
__device__ __forceinline__ void attn_step(
    const u16 (*Ksb)[64][32], const u16 (*Vsb)[64][32], u16* __restrict__ Pw,
    int k0, int qg, int l16, int quad, bool diag,
    const bf16x8 (&qf)[2], f32x4 (&o)[4], float (&lsum)[4])
{
    f32x4 s[4];
    for (int kt = 0; kt < 4; kt++) {
        f32x4 a = {0.f, 0.f, 0.f, 0.f};
        a = __builtin_amdgcn_mfma_f32_16x16x32_bf16(qf[0], *(const bf16x8*)&Ksb[0][kt * 16 + l16][quad * 8], a, 0, 0, 0);
        a = __builtin_amdgcn_mfma_f32_16x16x32_bf16(qf[1], *(const bf16x8*)&Ksb[1][kt * 16 + l16][quad * 8], a, 0, 0, 0);
        s[kt] = a;
    }
    if (diag) {
        for (int kt = 0; kt < 4; kt++) {
            const int kg = k0 + kt * 16 + l16;
            for (int r = 0; r < 4; r++) {
                float p = (kg <= qg + r) ? __builtin_amdgcn_exp2f(s[kt][r]) : 0.f;
                union { float f; unsigned u; } c; c.f = p;
                union { unsigned u; float f; } tf; tf.u = c.u & 0xFFFF0000u;
                lsum[r] += tf.f;
                Pw[(quad * 4 + r) * 72 + kt * 16 + l16] = (u16)(c.u >> 16);
            }
        }
    } else {
        for (int kt = 0; kt < 4; kt++)
            for (int r = 0; r < 4; r++) {
                float p = __builtin_amdgcn_exp2f(s[kt][r]);
                union { float f; unsigned u; } c; c.f = p;
                union { unsigned u; float f; } tf; tf.u = c.u & 0xFFFF0000u;
                lsum[r] += tf.f;
                Pw[(quad * 4 + r) * 72 + kt * 16 + l16] = (u16)(c.u >> 16);
            }
    }
    bf16x8 pa0 = *(const bf16x8*)&Pw[l16 * 72 + quad * 8];
    bf16x8 pa1 = *(const bf16x8*)&Pw[l16 * 72 + 32 + quad * 8];
    for (int dc = 0; dc < 4; dc++) {
        bf16x8 v0 = *(const bf16x8*)&Vsb[0][dc * 16 + l16][quad * 8];
        bf16x8 v1 = *(const bf16x8*)&Vsb[1][dc * 16 + l16][quad * 8];
        o[dc] = __builtin_amdgcn_mfma_f32_16x16x32_bf16(pa0, v0, o[dc], 0, 0, 0);
        o[dc] = __builtin_amdgcn_mfma_f32_16x16x32_bf16(pa1, v1, o[dc], 0, 0, 0);
    }
}

__global__ __launch_bounds__(256) void attn_kernel(
    const u16* __restrict__ Qp, const u16* __restrict__ Kp,
    const u16* __restrict__ VTg, u16* __restrict__ Hb)
{
    __shared__ __align__(16) u16 Ks[2][2][64][32];
    __shared__ __align__(16) u16 Vs[2][2][64][32];
    __shared__ __align__(16) u16 Pl[4][16][72];
    const int tid = threadIdx.x;
    const int wave = tid >> 6, lane = tid & 63;
    const int quad = lane >> 4, l16 = lane & 15;
    const int bh = ((blockIdx.x & 7) << 2) | ((blockIdx.x >> 3) & 3);
    const int qt = 31 - (blockIdx.x >> 5);           // heavy tiles first
    const int nk = qt + 1;
    const size_t kbase = (size_t)bh * 2048 * 64;
    const u16* Vt = VTg + (size_t)bh * 64 * 2048;
    u16* Pw = &Pl[wave][0][0];

    const int qrow = qt * 64 + wave * 16;
    bf16x8 qf[2];
    for (int c = 0; c < 2; c++)
        qf[c] = *(const bf16x8*)&Qp[kbase + (size_t)(qrow + l16) * 64 + c * 32 + quad * 8];

    f32x4 o[4] = {};
    float ls[4] = {0.f, 0.f, 0.f, 0.f};
    const int qg = qrow + quad * 4;

    const int srow = tid >> 2, sc8 = (tid & 3) * 8;
#define ISSUE(k0v, b) do {                                                      \
        ASYNC16(&Kp[kbase + (size_t)((k0v) + srow) * 64 + sc8],      &Ks[b][0][srow][sc8]); \
        ASYNC16(&Kp[kbase + (size_t)((k0v) + srow) * 64 + 32 + sc8], &Ks[b][1][srow][sc8]); \
        ASYNC16(&Vt[(size_t)srow * 2048 + (k0v) + sc8],              &Vs[b][0][srow][sc8]); \
        ASYNC16(&Vt[(size_t)srow * 2048 + (k0v) + 32 + sc8],         &Vs[b][1][srow][sc8]); \
    } while (0)

    ISSUE(0, 0);
    for (int g = 0; g < nk; g++) {
        __syncthreads();   // drains DMA issued at g-1; guards buffer reuse
        if (g + 1 < nk) ISSUE((g + 1) * 64, (g + 1) & 1);
        const int cur = g & 1;
        attn_step(Ks[cur], Vs[cur], Pw, g * 64, qg, l16, quad, g == nk - 1, qf, o, ls);
    }
#undef ISSUE

    float rl[4];
    for (int r = 0; r < 4; r++) {
        float t = ls[r];
        t += __shfl_xor(t, 1, 64);
        t += __shfl_xor(t, 2, 64);
        t += __shfl_xor(t, 4, 64);
        t += __shfl_xor(t, 8, 64);
        rl[r] = 1.f / t;
    }
    const int b = bh >> 4, h = bh & 15;
    for (int dc = 0; dc < 4; dc++)
        for (int r = 0; r < 4; r++) {
            int t = qrow + quad * 4 + r;
            Hb[((size_t)(b * 2048 + t)) * 1024 + h * 64 + dc * 16 + l16] = f2bf(o[dc][r] * rl[r]);
        }
}

// ---------------- layernorm (row = block), optional bf16 copy ----------------
__global__ __launch_bounds__(256) void ln_kernel(
    float* __restrict__ y, const float* __restrict__ g, const float* __restrict__ be,
    u16* __restrict__ bf_out)
{
    __shared__ float red[8];
    const int row = blockIdx.x, tid = threadIdx.x;
    float4 v = *(const float4*)&y[(size_t)row * 1024 + tid * 4];
    float sum = v.x + v.y + v.z + v.w;
    float sq  = v.x * v.x + v.y * v.y + v.z * v.z + v.w * v.w;
    for (int off = 1; off < 64; off <<= 1) {
        sum += __shfl_xor(sum, off, 64);
        sq  += __shfl_xor(sq,  off, 64);
    }
    int wave = tid >> 6;
    if ((tid & 63) == 0) { red[wave * 2] = sum; red[wave * 2 + 1] = sq; }
    __syncthreads();
    sum = red[0] + red[2] + red[4] + red[6];
    sq  = red[1] + red[3] + red[5] + red[7];
    float mu = sum * (1.f / 1024.f);
    float var = sq * (1.f / 1024.f) - mu * mu;
    float rstd = rsqrtf(var + 1e-5f);
    float4 gv = *(const float4*)&g[tid * 4];
    float4 bv = *(const float4*)&be[tid * 4];
    float4 ov;
    ov.x = (v.x - mu) * rstd * gv.x + bv.x;
    ov.y = (v.y - mu) * rstd * gv.y + bv.y;
    ov.z = (v.z - mu) * rstd * gv.z + bv.z;
    ov.w = (v.w - mu) * rstd * gv.w + bv.w;
    *(float4*)&y[(size_t)row * 1024 + tid * 4] = ov;
    if (bf_out) {
        ushort4 ob;
        ob.x = f2bf(ov.x); ob.y = f2bf(ov.y); ob.z = f2bf(ov.z); ob.w = f2bf(ov.w);
        *(ushort4*)&bf_out[(size_t)row * 1024 + tid * 4] = ob;
    }
}

// ---------------- launch ----------------
extern "C" void kernel_launch(void* const* d_in, const int* in_sizes, int n_in,
                              void* d_out, int out_size, void* d_ws, size_t ws_size,
                              hipStream_t stream)
{
    const float* x     = (const float*)d_in[0];
    const float* Wqkv  = (const float*)d_in[1];
    const float* bqkv  = (const float*)d_in[2];
    const float* Wout  = (const float*)d_in[3];
    const float* bout  = (const float*)d_in[4];
    const float* g1    = (const float*)d_in[5];
    const float* be1   = (const float*)d_in[6];
    const float* Wff1  = (const float*)d_in[7];
    const float* bff1  = (const float*)d_in[8];
    const float* Wff2  = (const float*)d_in[9];
    const float* bff2  = (const float*)d_in[10];
    const float* g2    = (const float*)d_in[11];
    const float* be2   = (const float*)d_in[12];
    float* out = (float*)d_out;

    char* wsb = (char*)d_ws;
    u16* WqkvT = (u16*)(wsb + 0);                   //  6 MB [3072,1024]
    u16* WoutT = (u16*)(wsb + 6291456);             //  2 MB [1024,1024]
    u16* Wff1T = (u16*)(wsb + 8388608);             //  4 MB [2048,1024]
    u16* Wff2T = (u16*)(wsb + 12582912);            //  4 MB [1024,2048]
    u16* xb    = (u16*)(wsb + 16777216);            //  8 MB [4096,1024]; reused as VT
    u16* Qp    = (u16*)(wsb + 25165824);            //  8 MB [B,H,T,D] bf16
    u16* Kp    = (u16*)(wsb + 33554432);            //  8 MB bf16
    u16* Vp    = (u16*)(wsb + 41943040);            //  8 MB bf16
    u16* Hb    = (u16*)(wsb + 50331648);            //  8 MB [4096,1024] bf16
    u16* x1b   = (u16*)(wsb + 58720256);            //  8 MB [4096,1024] bf16
    u16* ff1b  = (u16*)(wsb + 67108864);            // 16 MB [4096,2048] bf16
    float* y1  = (float*)(wsb + 83886080);          // 16 MB fp32 [4096,1024]
    u16* VTg   = xb;                                // V^T bf16 [bh][d][t]

    // fused weight prep (4 transposes in 1 launch) + x convert
    hipLaunchKernelGGL(prep_weights, dim3(8192), dim3(32, 8), 0, stream,
                       Wqkv, WqkvT, Wout, WoutT, Wff1, Wff1T, Wff2, Wff2T);
    hipLaunchKernelGGL(convert_bf16, dim3(4096), dim3(256), 0, stream, x, xb);

    // QKV projection (Q pre-scaled by 0.125*log2e)
    hipLaunchKernelGGL((gemm_kernel<0>), dim3(24, 32), dim3(256), 0, stream,
                       xb, WqkvT, bqkv, nullptr, nullptr, 4096, 3072, 1024, Qp, Kp, Vp);
    // V transpose (overwrites xb — dead now)
    hipLaunchKernelGGL(vtrans_kernel, dim3(32, 32), dim3(64, 8), 0, stream, Vp, VTg);
    // attention (v7)
    hipLaunchKernelGGL(attn_kernel, dim3(1024), dim3(256), 0, stream, Qp, Kp, VTg, Hb);
    // out projection + residual (x) -> y1 fp32   (64x128, 512 blocks)
    hipLaunchKernelGGL((gemm64_kernel<1>), dim3(8, 64), dim3(256), 0, stream,
                       Hb, WoutT, bout, (void*)y1, x, 4096, 1024, 1024);
    // LN1 in-place on y1, emit bf16 x1b
    hipLaunchKernelGGL(ln_kernel, dim3(4096), dim3(256), 0, stream, y1, g1, be1, x1b);
    // FF1 + relu -> ff1b bf16   (64x128, 1024 blocks => 4 blocks/CU)
    hipLaunchKernelGGL((gemm64_kernel<2>), dim3(16, 64), dim3(256), 0, stream,
                       x1b, Wff1T, bff1, (void*)ff1b, nullptr, 4096, 2048, 1024);
    // FF2 + residual (y1 = x1 fp32) -> d_out fp32   (64x128, 512 blocks)
    hipLaunchKernelGGL((gemm64_kernel<1>), dim3(8, 64), dim3(256), 0, stream,
                       ff1b, Wff2T, bff2, (void*)out, y1, 4096, 1024, 2048);
    // LN2 in-place on d_out
    hipLaunchKernelGGL(ln_kernel, dim3(4096), dim3(256), 0, stream, out, g2, be2, (u16*)nullptr);
}

// Round 11
// 291.340 us; speedup vs baseline: 1.0358x; 1.0054x over previous
//
#include <hip/hip_runtime.h>

typedef __bf16 bf16x8 __attribute__((ext_vector_type(8)));
typedef __bf16 bf16x4 __attribute__((ext_vector_type(4)));
typedef float f32x4 __attribute__((ext_vector_type(4)));
typedef unsigned short u16;

#define ASYNC16(gp, lp) __builtin_amdgcn_global_load_lds( \
    (__attribute__((address_space(1))) void*)(gp),        \
    (__attribute__((address_space(3))) void*)(lp), 16, 0, 0)

// ---------------- helpers ----------------
static __device__ __forceinline__ u16 f2bf(float f) {
    union { float f; unsigned u; } v; v.f = f;
    unsigned r = v.u + 0x7FFFu + ((v.u >> 16) & 1u);   // RNE
    return (u16)(r >> 16);
}

#define QSCALE 0.18033688011112042f  /* 0.125 * log2(e) */

// ---------------- fused weight transpose+convert + x convert (1 launch) -------
// blocks 0..8191: out[n*K+k] = bf16(in[k*N+n]) for the 4 weights
// blocks 8192..9215: straight x -> bf16 convert
__global__ void prep_weights(const float* __restrict__ W0, u16* __restrict__ O0,
                             const float* __restrict__ W1, u16* __restrict__ O1,
                             const float* __restrict__ W2, u16* __restrict__ O2,
                             const float* __restrict__ W3, u16* __restrict__ O3,
                             const float* __restrict__ X,  u16* __restrict__ XO) {
    int id = blockIdx.x;
    int t = threadIdx.y * 32 + threadIdx.x;
    if (id >= 8192) {
        size_t base = (size_t)(id - 8192) * 4096 + (size_t)t * 4;
        for (int i = 0; i < 4; i++) {
            float4 v = *(const float4*)&X[base + i * 1024];
            ushort4 o;
            o.x = f2bf(v.x); o.y = f2bf(v.y); o.z = f2bf(v.z); o.w = f2bf(v.w);
            *(ushort4*)&XO[base + i * 1024] = o;
        }
        return;
    }
    __shared__ float tile[32][33];
    const float* in; u16* out; int K, N, bx, by;
    if (id < 3072)      { in = W0; out = O0; K = 1024; N = 3072; bx = id % 96; by = id / 96; }
    else if (id < 4096) { id -= 3072; in = W1; out = O1; K = 1024; N = 1024; bx = id % 32; by = id / 32; }
    else if (id < 6144) { id -= 4096; in = W2; out = O2; K = 1024; N = 2048; bx = id % 64; by = id / 64; }
    else                { id -= 6144; in = W3; out = O3; K = 2048; N = 1024; bx = id % 32; by = id / 32; }
    int n0 = bx * 32, k0 = by * 32;
    int tx = threadIdx.x, ty = threadIdx.y;
    for (int i = 0; i < 4; i++)
        tile[ty + 8 * i][tx] = in[(size_t)(k0 + ty + 8 * i) * N + n0 + tx];
    __syncthreads();
    for (int i = 0; i < 4; i++)
        out[(size_t)(n0 + ty + 8 * i) * K + k0 + tx] = f2bf(tile[tx][ty + 8 * i]);
}

// V [bh][t][d] -> VT [bh][d][t]   grid(32, 32) block(64,8)
__global__ void vtrans_kernel(const u16* __restrict__ Vp, u16* __restrict__ VT) {
    __shared__ u16 tile[64 * 66];
    const int bh = blockIdx.y, t0 = blockIdx.x * 64;
    const int tx = threadIdx.x, ty = threadIdx.y;
    const u16* src = Vp + (size_t)bh * 2048 * 64;
    u16* dst = VT + (size_t)bh * 64 * 2048;
    for (int i = 0; i < 8; i++)
        tile[(ty + 8 * i) * 66 + tx] = src[(size_t)(t0 + ty + 8 * i) * 64 + tx];
    __syncthreads();
    for (int i = 0; i < 8; i++) {
        int d = ty + 8 * i;
        dst[(size_t)d * 2048 + t0 + tx] = tile[tx * 66 + d];
    }
}

// ---------------- GEMM 128x128, single-barrier double-buffered pipeline ----------
// EPI 0: scatter to Q/K/V [B,H,T,D] bf16 (N=3072); Q scaled by QSCALE
template <int EPI>
__global__ __launch_bounds__(256) void gemm_kernel(
    const u16* __restrict__ A, const u16* __restrict__ BT,
    const float* __restrict__ bias, void* __restrict__ out0,
    const float* __restrict__ resid, int M, int N, int K,
    u16* __restrict__ q_out, u16* __restrict__ k_out, u16* __restrict__ v_out)
{
    __shared__ __align__(16) u16 As[2][128 * 32];
    __shared__ __align__(16) u16 Bs[2][128 * 32];
    const int tid = threadIdx.x;
    const int wave = tid >> 6, lane = tid & 63;
    const int quad = lane >> 4, l16 = lane & 15;
    const int m0 = blockIdx.y * 128, n0 = blockIdx.x * 128;
    const int wm = (wave >> 1) * 64, wn = (wave & 1) * 64;
    const int sr = tid >> 2, sc = (tid & 3) * 8;

    f32x4 acc[4][4] = {};

#define GISSUE(k0v, bb) do {                                                         \
        ASYNC16(&A[(size_t)(m0 + sr) * K + (k0v) + sc],       &As[bb][sr * 32 + sc]);        \
        ASYNC16(&A[(size_t)(m0 + sr + 64) * K + (k0v) + sc],  &As[bb][(sr + 64) * 32 + sc]); \
        ASYNC16(&BT[(size_t)(n0 + sr) * K + (k0v) + sc],      &Bs[bb][sr * 32 + sc]);        \
        ASYNC16(&BT[(size_t)(n0 + sr + 64) * K + (k0v) + sc], &Bs[bb][(sr + 64) * 32 + sc]); \
    } while (0)

    const int nk = K >> 5;
    GISSUE(0, 0);
    for (int it = 0; it < nk; it++) {
        __syncthreads();
        if (it + 1 < nk) GISSUE((it + 1) * 32, (it + 1) & 1);
        const u16* Ab = As[it & 1];
        const u16* Bb = Bs[it & 1];
        bf16x8 af[4], bfr[4];
        for (int i = 0; i < 4; i++) {
            af[i]  = *(const bf16x8*)&Ab[(wm + i * 16 + l16) * 32 + quad * 8];
            bfr[i] = *(const bf16x8*)&Bb[(wn + i * 16 + l16) * 32 + quad * 8];
        }
        for (int i = 0; i < 4; i++)
            for (int j = 0; j < 4; j++)
                acc[i][j] = __builtin_amdgcn_mfma_f32_16x16x32_bf16(af[i], bfr[j], acc[i][j], 0, 0, 0);
    }
#undef GISSUE

    for (int i = 0; i < 4; i++) {
        int mbase = m0 + wm + i * 16 + quad * 4;
        for (int j = 0; j < 4; j++) {
            int n = n0 + wn + j * 16 + l16;
            float bv = bias[n];
            for (int r = 0; r < 4; r++) {
                int m = mbase + r;
                float v = acc[i][j][r] + bv;
                if (EPI == 0) {
                    int s = n >> 10, rr = n & 1023, h = rr >> 6, d = rr & 63;
                    int b = m >> 11, t = m & 2047;
                    if (s == 0) v *= QSCALE;
                    u16* dst = (s == 0) ? q_out : (s == 1) ? k_out : v_out;
                    dst[((size_t)((b * 16 + h) * 2048 + t)) * 64 + d] = f2bf(v);
                } else if (EPI == 1) {
                    ((float*)out0)[(size_t)m * N + n] = v + resid[(size_t)m * N + n];
                } else {
                    ((u16*)out0)[(size_t)m * N + n] = f2bf(fmaxf(v, 0.f));
                }
            }
        }
    }
}

// ---------------- GEMM 64x128 (FF1: 1024 blocks => 4 blocks/CU) -------
template <int EPI>
__global__ __launch_bounds__(256) void gemm64_kernel(
    const u16* __restrict__ A, const u16* __restrict__ BT,
    const float* __restrict__ bias, void* __restrict__ out0,
    const float* __restrict__ resid, int M, int N, int K)
{
    __shared__ __align__(16) u16 As[2][64 * 32];
    __shared__ __align__(16) u16 Bs[2][128 * 32];
    const int tid = threadIdx.x;
    const int wave = tid >> 6, lane = tid & 63;
    const int quad = lane >> 4, l16 = lane & 15;
    const int m0 = blockIdx.y * 64, n0 = blockIdx.x * 128;
    const int wn = wave * 32;
    const int sr = tid >> 2, sc = (tid & 3) * 8;

    f32x4 acc[4][2] = {};

#define GISSUE(k0v, bb) do {                                                         \
        ASYNC16(&A[(size_t)(m0 + sr) * K + (k0v) + sc],       &As[bb][sr * 32 + sc]);        \
        ASYNC16(&BT[(size_t)(n0 + sr) * K + (k0v) + sc],      &Bs[bb][sr * 32 + sc]);        \
        ASYNC16(&BT[(size_t)(n0 + sr + 64) * K + (k0v) + sc], &Bs[bb][(sr + 64) * 32 + sc]); \
    } while (0)

    const int nk = K >> 5;
    GISSUE(0, 0);
    for (int it = 0; it < nk; it++) {
        __syncthreads();
        if (it + 1 < nk) GISSUE((it + 1) * 32, (it + 1) & 1);
        const u16* Ab = As[it & 1];
        const u16* Bb = Bs[it & 1];
        bf16x8 af[4], bfr[2];
        for (int i = 0; i < 4; i++)
            af[i] = *(const bf16x8*)&Ab[(i * 16 + l16) * 32 + quad * 8];
        for (int j = 0; j < 2; j++)
            bfr[j] = *(const bf16x8*)&Bb[(wn + j * 16 + l16) * 32 + quad * 8];
        for (int i = 0; i < 4; i++)
            for (int j = 0; j < 2; j++)
                acc[i][j] = __builtin_amdgcn_mfma_f32_16x16x32_bf16(af[i], bfr[j], acc[i][j], 0, 0, 0);
    }
#undef GISSUE

    for (int i = 0; i < 4; i++) {
        int mbase = m0 + i * 16 + quad * 4;
        for (int j = 0; j < 2; j++) {
            int n = n0 + wn + j * 16 + l16;
            float bv = bias[n];
            for (int r = 0; r < 4; r++) {
                int m = mbase + r;
                float v = acc[i][j][r] + bv;
                if (EPI == 1)
                    ((float*)out0)[(size_t)m * N + n] = v + resid[(size_t)m * N + n];
                else
                    ((u16*)out0)[(size_t)m * N + n] = f2bf(fmaxf(v, 0.f));
            }
        }
    }
}

// ---------------- GEMM 64x64 (N=1024 GEMMs: 1024 blocks => 4 blocks/CU) -------
// fp32 out = acc + bias + resid, 16 KB LDS
__global__ __launch_bounds__(256) void gemm64x64_kernel(
    const u16* __restrict__ A, const u16* __restrict__ BT,
    const float* __restrict__ bias, float* __restrict__ out0,
    const float* __restrict__ resid, int M, int N, int K)
{
    __shared__ __align__(16) u16 As[2][64 * 32];
    __shared__ __align__(16) u16 Bs[2][64 * 32];
    const int tid = threadIdx.x;
    const int wave = tid >> 6, lane = tid & 63;
    const int quad = lane >> 4, l16 = lane & 15;
    const int m0 = blockIdx.y * 64, n0 = blockIdx.x * 64;
    const int wm = (wave >> 1) * 32, wn = (wave & 1) * 32;
    const int sr = tid >> 2, sc = (tid & 3) * 8;

    f32x4 acc[2][2] = {};

#define GISSUE(k0v, bb) do {                                                    \
        ASYNC16(&A[(size_t)(m0 + sr) * K + (k0v) + sc],  &As[bb][sr * 32 + sc]); \
        ASYNC16(&BT[(size_t)(n0 + sr) * K + (k0v) + sc], &Bs[bb][sr * 32 + sc]); \
    } while (0)

    const int nk = K >> 5;
    GISSUE(0, 0);
    for (int it = 0; it < nk; it++) {
        __syncthreads();
        if (it + 1 < nk) GISSUE((it + 1) * 32, (it + 1) & 1);
        const u16* Ab = As[it & 1];
        const u16* Bb = Bs[it & 1];
        bf16x8 af[2], bfr[2];
        for (int i = 0; i < 2; i++)
            af[i] = *(const bf16x8*)&Ab[(wm + i * 16 + l16) * 32 + quad * 8];
        for (int j = 0; j < 2; j++)
            bfr[j] = *(const bf16x8*)&Bb[(wn + j * 16 + l16) * 32 + quad * 8];
        for (int i = 0; i < 2; i++)
            for (int j = 0; j < 2; j++)
                acc[i][j] = __builtin_amdgcn_mfma_f32_16x16x32_bf16(af[i], bfr[j], acc[i][j], 0, 0, 0);
    }
#undef GISSUE

    for (int i = 0; i < 2; i++) {
        int mbase = m0 + wm + i * 16 + quad * 4;
        for (int j = 0; j < 2; j++) {
            int n = n0 + wn + j * 16 + l16;
            float bv = bias[n];
            for (int r = 0; r < 4; r++) {
                int m = mbase + r;
                out0[(size_t)m * N + n] = acc[i][j][r] + bv + resid[(size_t)m * N + n];
            }
        }
    }
}

// ---------------- flash attention v9: v7 + conflict-free P stride (68) ----------
// P row stride 68 u16 (34 dw): quad offset 4*34=136 ≡ 8 mod 32 -> the 4 quads'
// b16 writes cover banks {0-7},{8-15},{16-23},{24-31} = conflict-free.
// P-frag reads lose 16B alignment (136B rows) -> 2x ds_read_b64 each.
__device__ __forceinline__ void attn_step(
    const u16 (*Ksb)[64][32], const u16 (*Vsb)[64][32], u16* __restrict__ Pw,
    int k0, int qg, int l16, int quad, bool diag,
    const bf16x8 (&qf)[2], f32x4 (&o)[4], float (&lsum)[4])
{
    f32x4 s[4];
    for (int kt = 0; kt < 4; kt++) {
        f32x4 a = {0.f, 0.f, 0.f, 0.f};
        a = __builtin_amdgcn_mfma_f32_16x16x32_bf16(qf[0], *(const bf16x8*)&Ksb[0][kt * 16 + l16][quad * 8], a, 0, 0, 0);
        a = __builtin_amdgcn_mfma_f32_16x16x32_bf16(qf[1], *(const bf16x8*)&Ksb[1][kt * 16 + l16][quad * 8], a, 0, 0, 0);
        s[kt] = a;
    }
    if (diag) {
        for (int kt = 0; kt < 4; kt++) {
            const int kg = k0 + kt * 16 + l16;
            for (int r = 0; r < 4; r++) {
                float p = (kg <= qg + r) ? __builtin_amdgcn_exp2f(s[kt][r]) : 0.f;
                union { float f; unsigned u; } c; c.f = p;
                union { unsigned u; float f; } tf; tf.u = c.u & 0xFFFF0000u;
                lsum[r] += tf.f;
                Pw[(quad * 4 + r) * 68 + kt * 16 + l16] = (u16)(c.u >> 16);
            }
        }
    } else {
        for (int kt = 0; kt < 4; kt++)
            for (int r = 0; r < 4; r++) {
                float p = __builtin_amdgcn_exp2f(s[kt][r]);
                union { float f; unsigned u; } c; c.f = p;
                union { unsigned u; float f; } tf; tf.u = c.u & 0xFFFF0000u;
                lsum[r] += tf.f;
                Pw[(quad * 4 + r) * 68 + kt * 16 + l16] = (u16)(c.u >> 16);
            }
    }
    bf16x4 p00 = *(const bf16x4*)&Pw[l16 * 68 + quad * 8];
    bf16x4 p01 = *(const bf16x4*)&Pw[l16 * 68 + quad * 8 + 4];
    bf16x4 p10 = *(const bf16x4*)&Pw[l16 * 68 + 32 + quad * 8];
    bf16x4 p11 = *(const bf16x4*)&Pw[l16 * 68 + 32 + quad * 8 + 4];
    bf16x8 pa0 = __builtin_shufflevector(p00, p01, 0, 1, 2, 3, 4, 5, 6, 7);
    bf16x8 pa1 = __builtin_shufflevector(p10, p11, 0, 1, 2, 3, 4, 5, 6, 7);
    for (int dc = 0; dc < 4; dc++) {
        bf16x8 v0 = *(const bf16x8*)&Vsb[0][dc * 16 + l16][quad * 8];
        bf16x8 v1 = *(const bf16x8*)&Vsb[1][dc * 16 + l16][quad * 8];
        o[dc] = __builtin_amdgcn_mfma_f32_16x16x32_bf16(pa0, v0, o[dc], 0, 0, 0);
        o[dc] = __builtin_amdgcn_mfma_f32_16x16x32_bf16(pa1, v1, o[dc], 0, 0, 0);
    }
}

__global__ __launch_bounds__(256) void attn_kernel(
    const u16* __restrict__ Qp, const u16* __restrict__ Kp,
    const u16* __restrict__ VTg, u16* __restrict__ Hb)
{
    __shared__ __align__(16) u16 Ks[2][2][64][32];
    __shared__ __align__(16) u16 Vs[2][2][64][32];
    __shared__ __align__(16) u16 Pl[4][16][68];
    const int tid = threadIdx.x;
    const int wave = tid >> 6, lane = tid & 63;
    const int quad = lane >> 4, l16 = lane & 15;
    const int bh = ((blockIdx.x & 7) << 2) | ((blockIdx.x >> 3) & 3);
    const int qt = 31 - (blockIdx.x >> 5);           // heavy tiles first
    const int nk = qt + 1;
    const size_t kbase = (size_t)bh * 2048 * 64;
    const u16* Vt = VTg + (size_t)bh * 64 * 2048;
    u16* Pw = &Pl[wave][0][0];

    const int qrow = qt * 64 + wave * 16;
    bf16x8 qf[2];
    for (int c = 0; c < 2; c++)
        qf[c] = *(const bf16x8*)&Qp[kbase + (size_t)(qrow + l16) * 64 + c * 32 + quad * 8];

    f32x4 o[4] = {};
    float ls[4] = {0.f, 0.f, 0.f, 0.f};
    const int qg = qrow + quad * 4;

    const int srow = tid >> 2, sc8 = (tid & 3) * 8;
#define ISSUE(k0v, b) do {                                                      \
        ASYNC16(&Kp[kbase + (size_t)((k0v) + srow) * 64 + sc8],      &Ks[b][0][srow][sc8]); \
        ASYNC16(&Kp[kbase + (size_t)((k0v) + srow) * 64 + 32 + sc8], &Ks[b][1][srow][sc8]); \
        ASYNC16(&Vt[(size_t)srow * 2048 + (k0v) + sc8],              &Vs[b][0][srow][sc8]); \
        ASYNC16(&Vt[(size_t)srow * 2048 + (k0v) + 32 + sc8],         &Vs[b][1][srow][sc8]); \
    } while (0)

    ISSUE(0, 0);
    for (int g = 0; g < nk; g++) {
        __syncthreads();   // drains DMA issued at g-1; guards buffer reuse
        if (g + 1 < nk) ISSUE((g + 1) * 64, (g + 1) & 1);
        const int cur = g & 1;
        attn_step(Ks[cur], Vs[cur], Pw, g * 64, qg, l16, quad, g == nk - 1, qf, o, ls);
    }
#undef ISSUE

    float rl[4];
    for (int r = 0; r < 4; r++) {
        float t = ls[r];
        t += __shfl_xor(t, 1, 64);
        t += __shfl_xor(t, 2, 64);
        t += __shfl_xor(t, 4, 64);
        t += __shfl_xor(t, 8, 64);
        rl[r] = 1.f / t;
    }
    const int b = bh >> 4, h = bh & 15;
    for (int dc = 0; dc < 4; dc++)
        for (int r = 0; r < 4; r++) {
            int t = qrow + quad * 4 + r;
            Hb[((size_t)(b * 2048 + t)) * 1024 + h * 64 + dc * 16 + l16] = f2bf(o[dc][r] * rl[r]);
        }
}

// ---------------- layernorm (row = block), optional bf16 copy ----------------
__global__ __launch_bounds__(256) void ln_kernel(
    float* __restrict__ y, const float* __restrict__ g, const float* __restrict__ be,
    u16* __restrict__ bf_out)
{
    __shared__ float red[8];
    const int row = blockIdx.x, tid = threadIdx.x;
    float4 v = *(const float4*)&y[(size_t)row * 1024 + tid * 4];
    float sum = v.x + v.y + v.z + v.w;
    float sq  = v.x * v.x + v.y * v.y + v.z * v.z + v.w * v.w;
    for (int off = 1; off < 64; off <<= 1) {
        sum += __shfl_xor(sum, off, 64);
        sq  += __shfl_xor(sq,  off, 64);
    }
    int wave = tid >> 6;
    if ((tid & 63) == 0) { red[wave * 2] = sum; red[wave * 2 + 1] = sq; }
    __syncthreads();
    sum = red[0] + red[2] + red[4] + red[6];
    sq  = red[1] + red[3] + red[5] + red[7];
    float mu = sum * (1.f / 1024.f);
    float var = sq * (1.f / 1024.f) - mu * mu;
    float rstd = rsqrtf(var + 1e-5f);
    float4 gv = *(const float4*)&g[tid * 4];
    float4 bv = *(const float4*)&be[tid * 4];
    float4 ov;
    ov.x = (v.x - mu) * rstd * gv.x + bv.x;
    ov.y = (v.y - mu) * rstd * gv.y + bv.y;
    ov.z = (v.z - mu) * rstd * gv.z + bv.z;
    ov.w = (v.w - mu) * rstd * gv.w + bv.w;
    *(float4*)&y[(size_t)row * 1024 + tid * 4] = ov;
    if (bf_out) {
        ushort4 ob;
        ob.x = f2bf(ov.x); ob.y = f2bf(ov.y); ob.z = f2bf(ov.z); ob.w = f2bf(ov.w);
        *(ushort4*)&bf_out[(size_t)row * 1024 + tid * 4] = ob;
    }
}

// ---------------- launch ----------------
extern "C" void kernel_launch(void* const* d_in, const int* in_sizes, int n_in,
                              void* d_out, int out_size, void* d_ws, size_t ws_size,
                              hipStream_t stream)
{
    const float* x     = (const float*)d_in[0];
    const float* Wqkv  = (const float*)d_in[1];
    const float* bqkv  = (const float*)d_in[2];
    const float* Wout  = (const float*)d_in[3];
    const float* bout  = (const float*)d_in[4];
    const float* g1    = (const float*)d_in[5];
    const float* be1   = (const float*)d_in[6];
    const float* Wff1  = (const float*)d_in[7];
    const float* bff1  = (const float*)d_in[8];
    const float* Wff2  = (const float*)d_in[9];
    const float* bff2  = (const float*)d_in[10];
    const float* g2    = (const float*)d_in[11];
    const float* be2   = (const float*)d_in[12];
    float* out = (float*)d_out;

    char* wsb = (char*)d_ws;
    u16* WqkvT = (u16*)(wsb + 0);                   //  6 MB [3072,1024]
    u16* WoutT = (u16*)(wsb + 6291456);             //  2 MB [1024,1024]
    u16* Wff1T = (u16*)(wsb + 8388608);             //  4 MB [2048,1024]
    u16* Wff2T = (u16*)(wsb + 12582912);            //  4 MB [1024,2048]
    u16* xb    = (u16*)(wsb + 16777216);            //  8 MB [4096,1024]; reused as VT
    u16* Qp    = (u16*)(wsb + 25165824);            //  8 MB [B,H,T,D] bf16
    u16* Kp    = (u16*)(wsb + 33554432);            //  8 MB bf16
    u16* Vp    = (u16*)(wsb + 41943040);            //  8 MB bf16
    u16* Hb    = (u16*)(wsb + 50331648);            //  8 MB [4096,1024] bf16
    u16* x1b   = (u16*)(wsb + 58720256);            //  8 MB [4096,1024] bf16
    u16* ff1b  = (u16*)(wsb + 67108864);            // 16 MB [4096,2048] bf16
    float* y1  = (float*)(wsb + 83886080);          // 16 MB fp32 [4096,1024]
    u16* VTg   = xb;                                // V^T bf16 [bh][d][t]

    // fused weight prep (4 transposes + x convert in 1 launch)
    hipLaunchKernelGGL(prep_weights, dim3(9216), dim3(32, 8), 0, stream,
                       Wqkv, WqkvT, Wout, WoutT, Wff1, Wff1T, Wff2, Wff2T, x, xb);

    // QKV projection (Q pre-scaled by 0.125*log2e)
    hipLaunchKernelGGL((gemm_kernel<0>), dim3(24, 32), dim3(256), 0, stream,
                       xb, WqkvT, bqkv, nullptr, nullptr, 4096, 3072, 1024, Qp, Kp, Vp);
    // V transpose (overwrites xb — dead now)
    hipLaunchKernelGGL(vtrans_kernel, dim3(32, 32), dim3(64, 8), 0, stream, Vp, VTg);
    // attention (v9)
    hipLaunchKernelGGL(attn_kernel, dim3(1024), dim3(256), 0, stream, Qp, Kp, VTg, Hb);
    // out projection + residual (x) -> y1 fp32   (64x64, 1024 blocks)
    hipLaunchKernelGGL(gemm64x64_kernel, dim3(16, 64), dim3(256), 0, stream,
                       Hb, WoutT, bout, y1, x, 4096, 1024, 1024);
    // LN1 in-place on y1, emit bf16 x1b
    hipLaunchKernelGGL(ln_kernel, dim3(4096), dim3(256), 0, stream, y1, g1, be1, x1b);
    // FF1 + relu -> ff1b bf16   (64x128, 1024 blocks)
    hipLaunchKernelGGL((gemm64_kernel<2>), dim3(16, 64), dim3(256), 0, stream,
                       x1b, Wff1T, bff1, (void*)ff1b, nullptr, 4096, 2048, 1024);
    // FF2 + residual (y1 = x1 fp32) -> d_out fp32   (64x64, 1024 blocks)
    hipLaunchKernelGGL(gemm64x64_kernel, dim3(16, 64), dim3(256), 0, stream,
                       ff1b, Wff2T, bff2, out, y1, 4096, 1024, 2048);
    // LN2 in-place on d_out
    hipLaunchKernelGGL(ln_kernel, dim3(4096), dim3(256), 0, stream, out, g2, be2, (u16*)nullptr);
}

// Round 12
// 288.084 us; speedup vs baseline: 1.0475x; 1.0113x over previous
//
#include <hip/hip_runtime.h>

typedef __bf16 bf16x8 __attribute__((ext_vector_type(8)));
typedef float f32x4 __attribute__((ext_vector_type(4)));
typedef _Float16 h4 __attribute__((ext_vector_type(4)));
typedef unsigned short u16;

#define ASYNC16(gp, lp) __builtin_amdgcn_global_load_lds( \
    (__attribute__((address_space(1))) void*)(gp),        \
    (__attribute__((address_space(3))) void*)(lp), 16, 0, 0)

// ---------------- helpers ----------------
static __device__ __forceinline__ u16 f2bf(float f) {
    union { float f; unsigned u; } v; v.f = f;
    unsigned r = v.u + 0x7FFFu + ((v.u >> 16) & 1u);   // RNE
    return (u16)(r >> 16);
}
static __device__ __forceinline__ u16 f2h(float f) {
    _Float16 h = (_Float16)f;
    union { _Float16 h; u16 u; } c; c.h = h;
    return c.u;
}

#define QSCALE 0.18033688011112042f  /* 0.125 * log2(e) */

// ---------------- fused weight transpose+convert + x convert (1 launch) -------
__global__ void prep_weights(const float* __restrict__ W0, u16* __restrict__ O0,
                             const float* __restrict__ W1, u16* __restrict__ O1,
                             const float* __restrict__ W2, u16* __restrict__ O2,
                             const float* __restrict__ W3, u16* __restrict__ O3,
                             const float* __restrict__ X,  u16* __restrict__ XO) {
    int id = blockIdx.x;
    int t = threadIdx.y * 32 + threadIdx.x;
    if (id >= 8192) {
        size_t base = (size_t)(id - 8192) * 4096 + (size_t)t * 4;
        for (int i = 0; i < 4; i++) {
            float4 v = *(const float4*)&X[base + i * 1024];
            ushort4 o;
            o.x = f2bf(v.x); o.y = f2bf(v.y); o.z = f2bf(v.z); o.w = f2bf(v.w);
            *(ushort4*)&XO[base + i * 1024] = o;
        }
        return;
    }
    __shared__ float tile[32][33];
    const float* in; u16* out; int K, N, bx, by;
    if (id < 3072)      { in = W0; out = O0; K = 1024; N = 3072; bx = id % 96; by = id / 96; }
    else if (id < 4096) { id -= 3072; in = W1; out = O1; K = 1024; N = 1024; bx = id % 32; by = id / 32; }
    else if (id < 6144) { id -= 4096; in = W2; out = O2; K = 1024; N = 2048; bx = id % 64; by = id / 64; }
    else                { id -= 6144; in = W3; out = O3; K = 2048; N = 1024; bx = id % 32; by = id / 32; }
    int n0 = bx * 32, k0 = by * 32;
    int tx = threadIdx.x, ty = threadIdx.y;
    for (int i = 0; i < 4; i++)
        tile[ty + 8 * i][tx] = in[(size_t)(k0 + ty + 8 * i) * N + n0 + tx];
    __syncthreads();
    for (int i = 0; i < 4; i++)
        out[(size_t)(n0 + ty + 8 * i) * K + k0 + tx] = f2bf(tile[tx][ty + 8 * i]);
}

// V [bh][t][d] -> VT [bh][d][t]   grid(32, 32) block(64,8)  (u16 passthrough)
__global__ void vtrans_kernel(const u16* __restrict__ Vp, u16* __restrict__ VT) {
    __shared__ u16 tile[64 * 66];
    const int bh = blockIdx.y, t0 = blockIdx.x * 64;
    const int tx = threadIdx.x, ty = threadIdx.y;
    const u16* src = Vp + (size_t)bh * 2048 * 64;
    u16* dst = VT + (size_t)bh * 64 * 2048;
    for (int i = 0; i < 8; i++)
        tile[(ty + 8 * i) * 66 + tx] = src[(size_t)(t0 + ty + 8 * i) * 64 + tx];
    __syncthreads();
    for (int i = 0; i < 8; i++) {
        int d = ty + 8 * i;
        dst[(size_t)d * 2048 + t0 + tx] = tile[tx * 66 + d];
    }
}

// ---------------- GEMM 128x128, single-barrier double-buffered pipeline ----------
// EPI 0: scatter to Q/K (bf16) + V (f16) [B,H,T,D]; Q scaled by QSCALE
template <int EPI>
__global__ __launch_bounds__(256) void gemm_kernel(
    const u16* __restrict__ A, const u16* __restrict__ BT,
    const float* __restrict__ bias, void* __restrict__ out0,
    const float* __restrict__ resid, int M, int N, int K,
    u16* __restrict__ q_out, u16* __restrict__ k_out, u16* __restrict__ v_out)
{
    __shared__ __align__(16) u16 As[2][128 * 32];
    __shared__ __align__(16) u16 Bs[2][128 * 32];
    const int tid = threadIdx.x;
    const int wave = tid >> 6, lane = tid & 63;
    const int quad = lane >> 4, l16 = lane & 15;
    const int m0 = blockIdx.y * 128, n0 = blockIdx.x * 128;
    const int wm = (wave >> 1) * 64, wn = (wave & 1) * 64;
    const int sr = tid >> 2, sc = (tid & 3) * 8;

    f32x4 acc[4][4] = {};

#define GISSUE(k0v, bb) do {                                                         \
        ASYNC16(&A[(size_t)(m0 + sr) * K + (k0v) + sc],       &As[bb][sr * 32 + sc]);        \
        ASYNC16(&A[(size_t)(m0 + sr + 64) * K + (k0v) + sc],  &As[bb][(sr + 64) * 32 + sc]); \
        ASYNC16(&BT[(size_t)(n0 + sr) * K + (k0v) + sc],      &Bs[bb][sr * 32 + sc]);        \
        ASYNC16(&BT[(size_t)(n0 + sr + 64) * K + (k0v) + sc], &Bs[bb][(sr + 64) * 32 + sc]); \
    } while (0)

    const int nk = K >> 5;
    GISSUE(0, 0);
    for (int it = 0; it < nk; it++) {
        __syncthreads();
        if (it + 1 < nk) GISSUE((it + 1) * 32, (it + 1) & 1);
        const u16* Ab = As[it & 1];
        const u16* Bb = Bs[it & 1];
        bf16x8 af[4], bfr[4];
        for (int i = 0; i < 4; i++) {
            af[i]  = *(const bf16x8*)&Ab[(wm + i * 16 + l16) * 32 + quad * 8];
            bfr[i] = *(const bf16x8*)&Bb[(wn + i * 16 + l16) * 32 + quad * 8];
        }
        for (int i = 0; i < 4; i++)
            for (int j = 0; j < 4; j++)
                acc[i][j] = __builtin_amdgcn_mfma_f32_16x16x32_bf16(af[i], bfr[j], acc[i][j], 0, 0, 0);
    }
#undef GISSUE

    for (int i = 0; i < 4; i++) {
        int mbase = m0 + wm + i * 16 + quad * 4;
        for (int j = 0; j < 4; j++) {
            int n = n0 + wn + j * 16 + l16;
            float bv = bias[n];
            for (int r = 0; r < 4; r++) {
                int m = mbase + r;
                float v = acc[i][j][r] + bv;
                if (EPI == 0) {
                    int s = n >> 10, rr = n & 1023, h = rr >> 6, d = rr & 63;
                    int b = m >> 11, t = m & 2047;
                    if (s == 0) v *= QSCALE;
                    u16* dst = (s == 0) ? q_out : (s == 1) ? k_out : v_out;
                    u16 bits = (s == 2) ? f2h(v) : f2bf(v);
                    dst[((size_t)((b * 16 + h) * 2048 + t)) * 64 + d] = bits;
                } else if (EPI == 1) {
                    ((float*)out0)[(size_t)m * N + n] = v + resid[(size_t)m * N + n];
                } else {
                    ((u16*)out0)[(size_t)m * N + n] = f2bf(fmaxf(v, 0.f));
                }
            }
        }
    }
}

// ---------------- GEMM 64x128 (FF1: 1024 blocks => 4 blocks/CU) -------
template <int EPI>
__global__ __launch_bounds__(256) void gemm64_kernel(
    const u16* __restrict__ A, const u16* __restrict__ BT,
    const float* __restrict__ bias, void* __restrict__ out0,
    const float* __restrict__ resid, int M, int N, int K)
{
    __shared__ __align__(16) u16 As[2][64 * 32];
    __shared__ __align__(16) u16 Bs[2][128 * 32];
    const int tid = threadIdx.x;
    const int wave = tid >> 6, lane = tid & 63;
    const int quad = lane >> 4, l16 = lane & 15;
    const int m0 = blockIdx.y * 64, n0 = blockIdx.x * 128;
    const int wn = wave * 32;
    const int sr = tid >> 2, sc = (tid & 3) * 8;

    f32x4 acc[4][2] = {};

#define GISSUE(k0v, bb) do {                                                         \
        ASYNC16(&A[(size_t)(m0 + sr) * K + (k0v) + sc],       &As[bb][sr * 32 + sc]);        \
        ASYNC16(&BT[(size_t)(n0 + sr) * K + (k0v) + sc],      &Bs[bb][sr * 32 + sc]);        \
        ASYNC16(&BT[(size_t)(n0 + sr + 64) * K + (k0v) + sc], &Bs[bb][(sr + 64) * 32 + sc]); \
    } while (0)

    const int nk = K >> 5;
    GISSUE(0, 0);
    for (int it = 0; it < nk; it++) {
        __syncthreads();
        if (it + 1 < nk) GISSUE((it + 1) * 32, (it + 1) & 1);
        const u16* Ab = As[it & 1];
        const u16* Bb = Bs[it & 1];
        bf16x8 af[4], bfr[2];
        for (int i = 0; i < 4; i++)
            af[i] = *(const bf16x8*)&Ab[(i * 16 + l16) * 32 + quad * 8];
        for (int j = 0; j < 2; j++)
            bfr[j] = *(const bf16x8*)&Bb[(wn + j * 16 + l16) * 32 + quad * 8];
        for (int i = 0; i < 4; i++)
            for (int j = 0; j < 2; j++)
                acc[i][j] = __builtin_amdgcn_mfma_f32_16x16x32_bf16(af[i], bfr[j], acc[i][j], 0, 0, 0);
    }
#undef GISSUE

    for (int i = 0; i < 4; i++) {
        int mbase = m0 + i * 16 + quad * 4;
        for (int j = 0; j < 2; j++) {
            int n = n0 + wn + j * 16 + l16;
            float bv = bias[n];
            for (int r = 0; r < 4; r++) {
                int m = mbase + r;
                float v = acc[i][j][r] + bv;
                if (EPI == 1)
                    ((float*)out0)[(size_t)m * N + n] = v + resid[(size_t)m * N + n];
                else
                    ((u16*)out0)[(size_t)m * N + n] = f2bf(fmaxf(v, 0.f));
            }
        }
    }
}

// ---------------- GEMM 64x64 (N=1024 GEMMs: 1024 blocks => 4 blocks/CU) -------
__global__ __launch_bounds__(256) void gemm64x64_kernel(
    const u16* __restrict__ A, const u16* __restrict__ BT,
    const float* __restrict__ bias, float* __restrict__ out0,
    const float* __restrict__ resid, int M, int N, int K)
{
    __shared__ __align__(16) u16 As[2][64 * 32];
    __shared__ __align__(16) u16 Bs[2][64 * 32];
    const int tid = threadIdx.x;
    const int wave = tid >> 6, lane = tid & 63;
    const int quad = lane >> 4, l16 = lane & 15;
    const int m0 = blockIdx.y * 64, n0 = blockIdx.x * 64;
    const int wm = (wave >> 1) * 32, wn = (wave & 1) * 32;
    const int sr = tid >> 2, sc = (tid & 3) * 8;

    f32x4 acc[2][2] = {};

#define GISSUE(k0v, bb) do {                                                    \
        ASYNC16(&A[(size_t)(m0 + sr) * K + (k0v) + sc],  &As[bb][sr * 32 + sc]); \
        ASYNC16(&BT[(size_t)(n0 + sr) * K + (k0v) + sc], &Bs[bb][sr * 32 + sc]); \
    } while (0)

    const int nk = K >> 5;
    GISSUE(0, 0);
    for (int it = 0; it < nk; it++) {
        __syncthreads();
        if (it + 1 < nk) GISSUE((it + 1) * 32, (it + 1) & 1);
        const u16* Ab = As[it & 1];
        const u16* Bb = Bs[it & 1];
        bf16x8 af[2], bfr[2];
        for (int i = 0; i < 2; i++)
            af[i] = *(const bf16x8*)&Ab[(wm + i * 16 + l16) * 32 + quad * 8];
        for (int j = 0; j < 2; j++)
            bfr[j] = *(const bf16x8*)&Bb[(wn + j * 16 + l16) * 32 + quad * 8];
        for (int i = 0; i < 2; i++)
            for (int j = 0; j < 2; j++)
                acc[i][j] = __builtin_amdgcn_mfma_f32_16x16x32_bf16(af[i], bfr[j], acc[i][j], 0, 0, 0);
    }
#undef GISSUE

    for (int i = 0; i < 2; i++) {
        int mbase = m0 + wm + i * 16 + quad * 4;
        for (int j = 0; j < 2; j++) {
            int n = n0 + wn + j * 16 + l16;
            float bv = bias[n];
            for (int r = 0; r < 4; r++) {
                int m = mbase + r;
                out0[(size_t)m * N + n] = acc[i][j][r] + bv + resid[(size_t)m * N + n];
            }
        }
    }
}

// ---------------- flash attention v10: in-register P (v6 scheme) + padded V ----
// S^T = K*Q^T via 16x16x32 (A=K b128 from LDS, B=Q regs). S^T C-layout
// (lane l16=q, row t=quad*4+r) IS the 16x16x16f16 A-layout (k=quad*4+j):
// P never touches LDS (v6-verified numerics). V f16 in PADDED LDS
// [buf][panel][64][36]: 72B rows -> bank 18*l16 mod 32 all-distinct => the
// b64 V reads that killed v6 (8-way at 64B stride) become conflict-free.
// V staged via registers (pad breaks global_load_lds): load after barrier,
// ds_write after compute -> vmcnt wait hidden.
__global__ __launch_bounds__(256) void attn_kernel(
    const u16* __restrict__ Qp, const u16* __restrict__ Kp,
    const u16* __restrict__ VTg, u16* __restrict__ Hb)
{
    __shared__ __align__(16) u16 Ks[2][2][64][32];   // [buf][d-panel][t][d] bf16
    __shared__ __align__(16) u16 Vs[2][2][64][36];   // [buf][t-panel][d][t+pad] f16
    const int tid = threadIdx.x;
    const int wave = tid >> 6, lane = tid & 63;
    const int quad = lane >> 4, l16 = lane & 15;
    const int bh = ((blockIdx.x & 7) << 2) | ((blockIdx.x >> 3) & 3);
    const int qt = 31 - (blockIdx.x >> 5);           // heavy tiles first
    const int nk = qt + 1;
    const size_t kbase = (size_t)bh * 2048 * 64;
    const u16* Vt = VTg + (size_t)bh * 64 * 2048;

    const int qrow = qt * 64 + wave * 16;
    const int qg = qrow + l16;                       // this lane's q (S^T col)
    bf16x8 qf[2];
    for (int c = 0; c < 2; c++)
        qf[c] = *(const bf16x8*)&Qp[kbase + (size_t)(qrow + l16) * 64 + c * 32 + quad * 8];

    f32x4 o[4] = {};
    float lsum = 0.f;

    // staging assignments
    const int srow = tid >> 2, sc8 = (tid & 3) * 8;  // K rows
    const int vd = tid >> 2, vq = tid & 3;           // V: d row, t-quarter
    const int vp = vq >> 1, vw = (vq & 1) * 16;

#define KISSUE(k0v, b) do {                                                                 \
        ASYNC16(&Kp[kbase + (size_t)((k0v) + srow) * 64 + sc8],      &Ks[b][0][srow][sc8]); \
        ASYNC16(&Kp[kbase + (size_t)((k0v) + srow) * 64 + 32 + sc8], &Ks[b][1][srow][sc8]); \
    } while (0)
#define VLOAD(k0v) do {                                                           \
        vr0 = *(const uint4*)&Vt[(size_t)vd * 2048 + (k0v) + vq * 16];            \
        vr1 = *(const uint4*)&Vt[(size_t)vd * 2048 + (k0v) + vq * 16 + 8];        \
    } while (0)
#define VSTORE(b) do {                                                            \
        *(uint2*)&Vs[b][vp][vd][vw]      = make_uint2(vr0.x, vr0.y);              \
        *(uint2*)&Vs[b][vp][vd][vw + 4]  = make_uint2(vr0.z, vr0.w);              \
        *(uint2*)&Vs[b][vp][vd][vw + 8]  = make_uint2(vr1.x, vr1.y);              \
        *(uint2*)&Vs[b][vp][vd][vw + 12] = make_uint2(vr1.z, vr1.w);              \
    } while (0)

    uint4 vr0, vr1;
    VLOAD(0); KISSUE(0, 0); VSTORE(0);
    for (int g = 0; g < nk; g++) {
        __syncthreads();   // drains K DMA (g, issued at g-1) + makes Vs(g) writes visible
        const int cur = g & 1, nxt = cur ^ 1;
        const bool more = (g + 1 < nk);
        if (more) { VLOAD((g + 1) * 64); KISSUE((g + 1) * 64, nxt); }
        const int k0 = g * 64;
        const bool diag = (g == nk - 1);

        f32x4 st[4];
        for (int kt = 0; kt < 4; kt++) {
            f32x4 a = {0.f, 0.f, 0.f, 0.f};
            a = __builtin_amdgcn_mfma_f32_16x16x32_bf16(
                    *(const bf16x8*)&Ks[cur][0][kt * 16 + l16][quad * 8], qf[0], a, 0, 0, 0);
            a = __builtin_amdgcn_mfma_f32_16x16x32_bf16(
                    *(const bf16x8*)&Ks[cur][1][kt * 16 + l16][quad * 8], qf[1], a, 0, 0, 0);
            st[kt] = a;
        }
        for (int kt = 0; kt < 4; kt++) {
            h4 pa;
            if (diag) {
                for (int r = 0; r < 4; r++) {
                    int tg = k0 + kt * 16 + quad * 4 + r;
                    float p = (tg <= qg) ? __builtin_amdgcn_exp2f(st[kt][r]) : 0.f;
                    lsum += p; pa[r] = (_Float16)p;
                }
            } else {
                for (int r = 0; r < 4; r++) {
                    float p = __builtin_amdgcn_exp2f(st[kt][r]);
                    lsum += p; pa[r] = (_Float16)p;
                }
            }
            const int tp = kt >> 1, tw = (kt & 1) * 16 + quad * 4;
            for (int dc = 0; dc < 4; dc++) {
                h4 vb = *(const h4*)&Vs[cur][tp][dc * 16 + l16][tw];
                o[dc] = __builtin_amdgcn_mfma_f32_16x16x16f16(pa, vb, o[dc], 0, 0, 0);
            }
        }
        if (more) VSTORE(nxt);   // vmcnt wait lands here, after full compute
    }
#undef KISSUE
#undef VLOAD
#undef VSTORE

    // full row-sum for q=l16 (quads partition t-space), then broadcast to C-layout rows
    lsum += __shfl_xor(lsum, 16, 64);
    lsum += __shfl_xor(lsum, 32, 64);
    float rinv = 1.f / lsum;
    float rq[4];
    for (int r = 0; r < 4; r++)
        rq[r] = __shfl(rinv, quad * 4 + r, 64);

    const int b = bh >> 4, h = bh & 15;
    for (int dc = 0; dc < 4; dc++)
        for (int r = 0; r < 4; r++) {
            int q = qrow + quad * 4 + r;
            Hb[((size_t)(b * 2048 + q)) * 1024 + h * 64 + dc * 16 + l16] = f2bf(o[dc][r] * rq[r]);
        }
}

// ---------------- layernorm (row = block), optional bf16 copy ----------------
__global__ __launch_bounds__(256) void ln_kernel(
    float* __restrict__ y, const float* __restrict__ g, const float* __restrict__ be,
    u16* __restrict__ bf_out)
{
    __shared__ float red[8];
    const int row = blockIdx.x, tid = threadIdx.x;
    float4 v = *(const float4*)&y[(size_t)row * 1024 + tid * 4];
    float sum = v.x + v.y + v.z + v.w;
    float sq  = v.x * v.x + v.y * v.y + v.z * v.z + v.w * v.w;
    for (int off = 1; off < 64; off <<= 1) {
        sum += __shfl_xor(sum, off, 64);
        sq  += __shfl_xor(sq,  off, 64);
    }
    int wave = tid >> 6;
    if ((tid & 63) == 0) { red[wave * 2] = sum; red[wave * 2 + 1] = sq; }
    __syncthreads();
    sum = red[0] + red[2] + red[4] + red[6];
    sq  = red[1] + red[3] + red[5] + red[7];
    float mu = sum * (1.f / 1024.f);
    float var = sq * (1.f / 1024.f) - mu * mu;
    float rstd = rsqrtf(var + 1e-5f);
    float4 gv = *(const float4*)&g[tid * 4];
    float4 bv = *(const float4*)&be[tid * 4];
    float4 ov;
    ov.x = (v.x - mu) * rstd * gv.x + bv.x;
    ov.y = (v.y - mu) * rstd * gv.y + bv.y;
    ov.z = (v.z - mu) * rstd * gv.z + bv.z;
    ov.w = (v.w - mu) * rstd * gv.w + bv.w;
    *(float4*)&y[(size_t)row * 1024 + tid * 4] = ov;
    if (bf_out) {
        ushort4 ob;
        ob.x = f2bf(ov.x); ob.y = f2bf(ov.y); ob.z = f2bf(ov.z); ob.w = f2bf(ov.w);
        *(ushort4*)&bf_out[(size_t)row * 1024 + tid * 4] = ob;
    }
}

// ---------------- launch ----------------
extern "C" void kernel_launch(void* const* d_in, const int* in_sizes, int n_in,
                              void* d_out, int out_size, void* d_ws, size_t ws_size,
                              hipStream_t stream)
{
    const float* x     = (const float*)d_in[0];
    const float* Wqkv  = (const float*)d_in[1];
    const float* bqkv  = (const float*)d_in[2];
    const float* Wout  = (const float*)d_in[3];
    const float* bout  = (const float*)d_in[4];
    const float* g1    = (const float*)d_in[5];
    const float* be1   = (const float*)d_in[6];
    const float* Wff1  = (const float*)d_in[7];
    const float* bff1  = (const float*)d_in[8];
    const float* Wff2  = (const float*)d_in[9];
    const float* bff2  = (const float*)d_in[10];
    const float* g2    = (const float*)d_in[11];
    const float* be2   = (const float*)d_in[12];
    float* out = (float*)d_out;

    char* wsb = (char*)d_ws;
    u16* WqkvT = (u16*)(wsb + 0);                   //  6 MB [3072,1024]
    u16* WoutT = (u16*)(wsb + 6291456);             //  2 MB [1024,1024]
    u16* Wff1T = (u16*)(wsb + 8388608);             //  4 MB [2048,1024]
    u16* Wff2T = (u16*)(wsb + 12582912);            //  4 MB [1024,2048]
    u16* xb    = (u16*)(wsb + 16777216);            //  8 MB [4096,1024]; reused as VT
    u16* Qp    = (u16*)(wsb + 25165824);            //  8 MB [B,H,T,D] bf16
    u16* Kp    = (u16*)(wsb + 33554432);            //  8 MB bf16
    u16* Vp    = (u16*)(wsb + 41943040);            //  8 MB f16
    u16* Hb    = (u16*)(wsb + 50331648);            //  8 MB [4096,1024] bf16
    u16* x1b   = (u16*)(wsb + 58720256);            //  8 MB [4096,1024] bf16
    u16* ff1b  = (u16*)(wsb + 67108864);            // 16 MB [4096,2048] bf16
    float* y1  = (float*)(wsb + 83886080);          // 16 MB fp32 [4096,1024]
    u16* VTg   = xb;                                // V^T f16 [bh][d][t]

    // fused weight prep (4 transposes + x convert in 1 launch)
    hipLaunchKernelGGL(prep_weights, dim3(9216), dim3(32, 8), 0, stream,
                       Wqkv, WqkvT, Wout, WoutT, Wff1, Wff1T, Wff2, Wff2T, x, xb);

    // QKV projection (Q pre-scaled by 0.125*log2e; V stored f16)
    hipLaunchKernelGGL((gemm_kernel<0>), dim3(24, 32), dim3(256), 0, stream,
                       xb, WqkvT, bqkv, nullptr, nullptr, 4096, 3072, 1024, Qp, Kp, Vp);
    // V transpose (f16 passthrough; overwrites xb — dead now)
    hipLaunchKernelGGL(vtrans_kernel, dim3(32, 32), dim3(64, 8), 0, stream, Vp, VTg);
    // attention (v10)
    hipLaunchKernelGGL(attn_kernel, dim3(1024), dim3(256), 0, stream, Qp, Kp, VTg, Hb);
    // out projection + residual (x) -> y1 fp32   (64x64, 1024 blocks)
    hipLaunchKernelGGL(gemm64x64_kernel, dim3(16, 64), dim3(256), 0, stream,
                       Hb, WoutT, bout, y1, x, 4096, 1024, 1024);
    // LN1 in-place on y1, emit bf16 x1b
    hipLaunchKernelGGL(ln_kernel, dim3(4096), dim3(256), 0, stream, y1, g1, be1, x1b);
    // FF1 + relu -> ff1b bf16   (64x128, 1024 blocks)
    hipLaunchKernelGGL((gemm64_kernel<2>), dim3(16, 64), dim3(256), 0, stream,
                       x1b, Wff1T, bff1, (void*)ff1b, nullptr, 4096, 2048, 1024);
    // FF2 + residual (y1 = x1 fp32) -> d_out fp32   (64x64, 1024 blocks)
    hipLaunchKernelGGL(gemm64x64_kernel, dim3(16, 64), dim3(256), 0, stream,
                       ff1b, Wff2T, bff2, out, y1, 4096, 1024, 2048);
    // LN2 in-place on d_out
    hipLaunchKernelGGL(ln_kernel, dim3(4096), dim3(256), 0, stream, out, g2, be2, (u16*)nullptr);
}

// Round 13
// 280.265 us; speedup vs baseline: 1.0767x; 1.0279x over previous
//
#include <hip/hip_runtime.h>

typedef __bf16 bf16x8 __attribute__((ext_vector_type(8)));
typedef float f32x4 __attribute__((ext_vector_type(4)));
typedef _Float16 h4 __attribute__((ext_vector_type(4)));
typedef unsigned short u16;

#define ASYNC16(gp, lp) __builtin_amdgcn_global_load_lds( \
    (__attribute__((address_space(1))) void*)(gp),        \
    (__attribute__((address_space(3))) void*)(lp), 16, 0, 0)

// ---------------- helpers ----------------
static __device__ __forceinline__ u16 f2bf(float f) {
    union { float f; unsigned u; } v; v.f = f;
    unsigned r = v.u + 0x7FFFu + ((v.u >> 16) & 1u);   // RNE
    return (u16)(r >> 16);
}
static __device__ __forceinline__ u16 f2h(float f) {
    _Float16 h = (_Float16)f;
    union { _Float16 h; u16 u; } c; c.h = h;
    return c.u;
}
static __device__ __forceinline__ float bf2f(u16 b) {
    union { unsigned u; float f; } c; c.u = ((unsigned)b) << 16;
    return c.f;
}

#define QSCALE 0.18033688011112042f  /* 0.125 * log2(e) */

// ---------------- fused weight transpose+convert + x convert (1 launch) -------
__global__ void prep_weights(const float* __restrict__ W0, u16* __restrict__ O0,
                             const float* __restrict__ W1, u16* __restrict__ O1,
                             const float* __restrict__ W2, u16* __restrict__ O2,
                             const float* __restrict__ W3, u16* __restrict__ O3,
                             const float* __restrict__ X,  u16* __restrict__ XO) {
    int id = blockIdx.x;
    int t = threadIdx.y * 32 + threadIdx.x;
    if (id >= 8192) {
        size_t base = (size_t)(id - 8192) * 4096 + (size_t)t * 4;
        for (int i = 0; i < 4; i++) {
            float4 v = *(const float4*)&X[base + i * 1024];
            ushort4 o;
            o.x = f2bf(v.x); o.y = f2bf(v.y); o.z = f2bf(v.z); o.w = f2bf(v.w);
            *(ushort4*)&XO[base + i * 1024] = o;
        }
        return;
    }
    __shared__ float tile[32][33];
    const float* in; u16* out; int K, N, bx, by;
    if (id < 3072)      { in = W0; out = O0; K = 1024; N = 3072; bx = id % 96; by = id / 96; }
    else if (id < 4096) { id -= 3072; in = W1; out = O1; K = 1024; N = 1024; bx = id % 32; by = id / 32; }
    else if (id < 6144) { id -= 4096; in = W2; out = O2; K = 1024; N = 2048; bx = id % 64; by = id / 64; }
    else                { id -= 6144; in = W3; out = O3; K = 2048; N = 1024; bx = id % 32; by = id / 32; }
    int n0 = bx * 32, k0 = by * 32;
    int tx = threadIdx.x, ty = threadIdx.y;
    for (int i = 0; i < 4; i++)
        tile[ty + 8 * i][tx] = in[(size_t)(k0 + ty + 8 * i) * N + n0 + tx];
    __syncthreads();
    for (int i = 0; i < 4; i++)
        out[(size_t)(n0 + ty + 8 * i) * K + k0 + tx] = f2bf(tile[tx][ty + 8 * i]);
}

// V [bh][t][d] -> VT [bh][d][t]   grid(32, 32) block(64,8)  (u16 passthrough)
__global__ void vtrans_kernel(const u16* __restrict__ Vp, u16* __restrict__ VT) {
    __shared__ u16 tile[64 * 66];
    const int bh = blockIdx.y, t0 = blockIdx.x * 64;
    const int tx = threadIdx.x, ty = threadIdx.y;
    const u16* src = Vp + (size_t)bh * 2048 * 64;
    u16* dst = VT + (size_t)bh * 64 * 2048;
    for (int i = 0; i < 8; i++)
        tile[(ty + 8 * i) * 66 + tx] = src[(size_t)(t0 + ty + 8 * i) * 64 + tx];
    __syncthreads();
    for (int i = 0; i < 8; i++) {
        int d = ty + 8 * i;
        dst[(size_t)d * 2048 + t0 + tx] = tile[tx * 66 + d];
    }
}

// ---------------- GEMM 128x128, single-barrier double-buffered pipeline ----------
// EPI 0: scatter to Q/K (bf16) + V (f16) [B,H,T,D]; Q scaled by QSCALE
template <int EPI>
__global__ __launch_bounds__(256) void gemm_kernel(
    const u16* __restrict__ A, const u16* __restrict__ BT,
    const float* __restrict__ bias, void* __restrict__ out0,
    const float* __restrict__ resid, int M, int N, int K,
    u16* __restrict__ q_out, u16* __restrict__ k_out, u16* __restrict__ v_out)
{
    __shared__ __align__(16) u16 As[2][128 * 32];
    __shared__ __align__(16) u16 Bs[2][128 * 32];
    const int tid = threadIdx.x;
    const int wave = tid >> 6, lane = tid & 63;
    const int quad = lane >> 4, l16 = lane & 15;
    const int m0 = blockIdx.y * 128, n0 = blockIdx.x * 128;
    const int wm = (wave >> 1) * 64, wn = (wave & 1) * 64;
    const int sr = tid >> 2, sc = (tid & 3) * 8;

    f32x4 acc[4][4] = {};

#define GISSUE(k0v, bb) do {                                                         \
        ASYNC16(&A[(size_t)(m0 + sr) * K + (k0v) + sc],       &As[bb][sr * 32 + sc]);        \
        ASYNC16(&A[(size_t)(m0 + sr + 64) * K + (k0v) + sc],  &As[bb][(sr + 64) * 32 + sc]); \
        ASYNC16(&BT[(size_t)(n0 + sr) * K + (k0v) + sc],      &Bs[bb][sr * 32 + sc]);        \
        ASYNC16(&BT[(size_t)(n0 + sr + 64) * K + (k0v) + sc], &Bs[bb][(sr + 64) * 32 + sc]); \
    } while (0)

    const int nk = K >> 5;
    GISSUE(0, 0);
    for (int it = 0; it < nk; it++) {
        __syncthreads();
        if (it + 1 < nk) GISSUE((it + 1) * 32, (it + 1) & 1);
        const u16* Ab = As[it & 1];
        const u16* Bb = Bs[it & 1];
        bf16x8 af[4], bfr[4];
        for (int i = 0; i < 4; i++) {
            af[i]  = *(const bf16x8*)&Ab[(wm + i * 16 + l16) * 32 + quad * 8];
            bfr[i] = *(const bf16x8*)&Bb[(wn + i * 16 + l16) * 32 + quad * 8];
        }
        for (int i = 0; i < 4; i++)
            for (int j = 0; j < 4; j++)
                acc[i][j] = __builtin_amdgcn_mfma_f32_16x16x32_bf16(af[i], bfr[j], acc[i][j], 0, 0, 0);
    }
#undef GISSUE

    for (int i = 0; i < 4; i++) {
        int mbase = m0 + wm + i * 16 + quad * 4;
        for (int j = 0; j < 4; j++) {
            int n = n0 + wn + j * 16 + l16;
            float bv = bias[n];
            for (int r = 0; r < 4; r++) {
                int m = mbase + r;
                float v = acc[i][j][r] + bv;
                if (EPI == 0) {
                    int s = n >> 10, rr = n & 1023, h = rr >> 6, d = rr & 63;
                    int b = m >> 11, t = m & 2047;
                    if (s == 0) v *= QSCALE;
                    u16* dst = (s == 0) ? q_out : (s == 1) ? k_out : v_out;
                    u16 bits = (s == 2) ? f2h(v) : f2bf(v);
                    dst[((size_t)((b * 16 + h) * 2048 + t)) * 64 + d] = bits;
                } else if (EPI == 1) {
                    ((float*)out0)[(size_t)m * N + n] = v + resid[(size_t)m * N + n];
                } else {
                    ((u16*)out0)[(size_t)m * N + n] = f2bf(fmaxf(v, 0.f));
                }
            }
        }
    }
}

// ---------------- GEMM 64x128 (FF1: 1024 blocks => 4 blocks/CU) -------
template <int EPI>
__global__ __launch_bounds__(256) void gemm64_kernel(
    const u16* __restrict__ A, const u16* __restrict__ BT,
    const float* __restrict__ bias, void* __restrict__ out0,
    const float* __restrict__ resid, int M, int N, int K)
{
    __shared__ __align__(16) u16 As[2][64 * 32];
    __shared__ __align__(16) u16 Bs[2][128 * 32];
    const int tid = threadIdx.x;
    const int wave = tid >> 6, lane = tid & 63;
    const int quad = lane >> 4, l16 = lane & 15;
    const int m0 = blockIdx.y * 64, n0 = blockIdx.x * 128;
    const int wn = wave * 32;
    const int sr = tid >> 2, sc = (tid & 3) * 8;

    f32x4 acc[4][2] = {};

#define GISSUE(k0v, bb) do {                                                         \
        ASYNC16(&A[(size_t)(m0 + sr) * K + (k0v) + sc],       &As[bb][sr * 32 + sc]);        \
        ASYNC16(&BT[(size_t)(n0 + sr) * K + (k0v) + sc],      &Bs[bb][sr * 32 + sc]);        \
        ASYNC16(&BT[(size_t)(n0 + sr + 64) * K + (k0v) + sc], &Bs[bb][(sr + 64) * 32 + sc]); \
    } while (0)

    const int nk = K >> 5;
    GISSUE(0, 0);
    for (int it = 0; it < nk; it++) {
        __syncthreads();
        if (it + 1 < nk) GISSUE((it + 1) * 32, (it + 1) & 1);
        const u16* Ab = As[it & 1];
        const u16* Bb = Bs[it & 1];
        bf16x8 af[4], bfr[2];
        for (int i = 0; i < 4; i++)
            af[i] = *(const bf16x8*)&Ab[(i * 16 + l16) * 32 + quad * 8];
        for (int j = 0; j < 2; j++)
            bfr[j] = *(const bf16x8*)&Bb[(wn + j * 16 + l16) * 32 + quad * 8];
        for (int i = 0; i < 4; i++)
            for (int j = 0; j < 2; j++)
                acc[i][j] = __builtin_amdgcn_mfma_f32_16x16x32_bf16(af[i], bfr[j], acc[i][j], 0, 0, 0);
    }
#undef GISSUE

    for (int i = 0; i < 4; i++) {
        int mbase = m0 + i * 16 + quad * 4;
        for (int j = 0; j < 2; j++) {
            int n = n0 + wn + j * 16 + l16;
            float bv = bias[n];
            for (int r = 0; r < 4; r++) {
                int m = mbase + r;
                float v = acc[i][j][r] + bv;
                if (EPI == 1)
                    ((float*)out0)[(size_t)m * N + n] = v + resid[(size_t)m * N + n];
                else
                    ((u16*)out0)[(size_t)m * N + n] = f2bf(fmaxf(v, 0.f));
            }
        }
    }
}

// ---------------- GEMM 64x64 v2: BK=64 two-panel (out-proj / FF2) -------
// [buf][k-panel][64][32] keeps 64B row stride (ASYNC16-compatible, proven
// bank profile) while halving barrier count: 8 MFMA per iteration.
// RESBF=0: fp32 resid; RESBF=1: bf16 resid.
template <int RESBF>
__global__ __launch_bounds__(256) void gemm64x64_kernel(
    const u16* __restrict__ A, const u16* __restrict__ BT,
    const float* __restrict__ bias, float* __restrict__ out0,
    const void* __restrict__ resid, int M, int N, int K)
{
    __shared__ __align__(16) u16 As[2][2][64][32];
    __shared__ __align__(16) u16 Bs[2][2][64][32];
    const int tid = threadIdx.x;
    const int wave = tid >> 6, lane = tid & 63;
    const int quad = lane >> 4, l16 = lane & 15;
    const int m0 = blockIdx.y * 64, n0 = blockIdx.x * 64;
    const int wm = (wave >> 1) * 32, wn = (wave & 1) * 32;
    const int sr = tid >> 2, sc = (tid & 3) * 8;

    f32x4 acc[2][2] = {};

#define GISSUE(k0v, bb) do {                                                          \
        ASYNC16(&A[(size_t)(m0 + sr) * K + (k0v) + sc],       &As[bb][0][sr][sc]);    \
        ASYNC16(&A[(size_t)(m0 + sr) * K + (k0v) + 32 + sc],  &As[bb][1][sr][sc]);    \
        ASYNC16(&BT[(size_t)(n0 + sr) * K + (k0v) + sc],      &Bs[bb][0][sr][sc]);    \
        ASYNC16(&BT[(size_t)(n0 + sr) * K + (k0v) + 32 + sc], &Bs[bb][1][sr][sc]);    \
    } while (0)

    const int nk = K >> 6;
    GISSUE(0, 0);
    for (int it = 0; it < nk; it++) {
        __syncthreads();
        if (it + 1 < nk) GISSUE((it + 1) * 64, (it + 1) & 1);
        const int cur = it & 1;
        for (int h = 0; h < 2; h++) {
            bf16x8 af[2], bfr[2];
            for (int i = 0; i < 2; i++)
                af[i] = *(const bf16x8*)&As[cur][h][wm + i * 16 + l16][quad * 8];
            for (int j = 0; j < 2; j++)
                bfr[j] = *(const bf16x8*)&Bs[cur][h][wn + j * 16 + l16][quad * 8];
            for (int i = 0; i < 2; i++)
                for (int j = 0; j < 2; j++)
                    acc[i][j] = __builtin_amdgcn_mfma_f32_16x16x32_bf16(af[i], bfr[j], acc[i][j], 0, 0, 0);
        }
    }
#undef GISSUE

    for (int i = 0; i < 2; i++) {
        int mbase = m0 + wm + i * 16 + quad * 4;
        for (int j = 0; j < 2; j++) {
            int n = n0 + wn + j * 16 + l16;
            float bv = bias[n];
            for (int r = 0; r < 4; r++) {
                int m = mbase + r;
                float rv = RESBF ? bf2f(((const u16*)resid)[(size_t)m * N + n])
                                 : ((const float*)resid)[(size_t)m * N + n];
                out0[(size_t)m * N + n] = acc[i][j][r] + bv + rv;
            }
        }
    }
}

// ---------------- flash attention v10: in-register P + padded V ----
__global__ __launch_bounds__(256) void attn_kernel(
    const u16* __restrict__ Qp, const u16* __restrict__ Kp,
    const u16* __restrict__ VTg, u16* __restrict__ Hb)
{
    __shared__ __align__(16) u16 Ks[2][2][64][32];   // [buf][d-panel][t][d] bf16
    __shared__ __align__(16) u16 Vs[2][2][64][36];   // [buf][t-panel][d][t+pad] f16
    const int tid = threadIdx.x;
    const int wave = tid >> 6, lane = tid & 63;
    const int quad = lane >> 4, l16 = lane & 15;
    const int bh = ((blockIdx.x & 7) << 2) | ((blockIdx.x >> 3) & 3);
    const int qt = 31 - (blockIdx.x >> 5);           // heavy tiles first
    const int nk = qt + 1;
    const size_t kbase = (size_t)bh * 2048 * 64;
    const u16* Vt = VTg + (size_t)bh * 64 * 2048;

    const int qrow = qt * 64 + wave * 16;
    const int qg = qrow + l16;                       // this lane's q (S^T col)
    bf16x8 qf[2];
    for (int c = 0; c < 2; c++)
        qf[c] = *(const bf16x8*)&Qp[kbase + (size_t)(qrow + l16) * 64 + c * 32 + quad * 8];

    f32x4 o[4] = {};
    float lsum = 0.f;

    const int srow = tid >> 2, sc8 = (tid & 3) * 8;  // K rows
    const int vd = tid >> 2, vq = tid & 3;           // V: d row, t-quarter
    const int vp = vq >> 1, vw = (vq & 1) * 16;

#define KISSUE(k0v, b) do {                                                                 \
        ASYNC16(&Kp[kbase + (size_t)((k0v) + srow) * 64 + sc8],      &Ks[b][0][srow][sc8]); \
        ASYNC16(&Kp[kbase + (size_t)((k0v) + srow) * 64 + 32 + sc8], &Ks[b][1][srow][sc8]); \
    } while (0)
#define VLOAD(k0v) do {                                                           \
        vr0 = *(const uint4*)&Vt[(size_t)vd * 2048 + (k0v) + vq * 16];            \
        vr1 = *(const uint4*)&Vt[(size_t)vd * 2048 + (k0v) + vq * 16 + 8];        \
    } while (0)
#define VSTORE(b) do {                                                            \
        *(uint2*)&Vs[b][vp][vd][vw]      = make_uint2(vr0.x, vr0.y);              \
        *(uint2*)&Vs[b][vp][vd][vw + 4]  = make_uint2(vr0.z, vr0.w);              \
        *(uint2*)&Vs[b][vp][vd][vw + 8]  = make_uint2(vr1.x, vr1.y);              \
        *(uint2*)&Vs[b][vp][vd][vw + 12] = make_uint2(vr1.z, vr1.w);              \
    } while (0)

    uint4 vr0, vr1;
    VLOAD(0); KISSUE(0, 0); VSTORE(0);
    for (int g = 0; g < nk; g++) {
        __syncthreads();
        const int cur = g & 1, nxt = cur ^ 1;
        const bool more = (g + 1 < nk);
        if (more) { VLOAD((g + 1) * 64); KISSUE((g + 1) * 64, nxt); }
        const int k0 = g * 64;
        const bool diag = (g == nk - 1);

        f32x4 st[4];
        for (int kt = 0; kt < 4; kt++) {
            f32x4 a = {0.f, 0.f, 0.f, 0.f};
            a = __builtin_amdgcn_mfma_f32_16x16x32_bf16(
                    *(const bf16x8*)&Ks[cur][0][kt * 16 + l16][quad * 8], qf[0], a, 0, 0, 0);
            a = __builtin_amdgcn_mfma_f32_16x16x32_bf16(
                    *(const bf16x8*)&Ks[cur][1][kt * 16 + l16][quad * 8], qf[1], a, 0, 0, 0);
            st[kt] = a;
        }
        for (int kt = 0; kt < 4; kt++) {
            h4 pa;
            if (diag) {
                for (int r = 0; r < 4; r++) {
                    int tg = k0 + kt * 16 + quad * 4 + r;
                    float p = (tg <= qg) ? __builtin_amdgcn_exp2f(st[kt][r]) : 0.f;
                    lsum += p; pa[r] = (_Float16)p;
                }
            } else {
                for (int r = 0; r < 4; r++) {
                    float p = __builtin_amdgcn_exp2f(st[kt][r]);
                    lsum += p; pa[r] = (_Float16)p;
                }
            }
            const int tp = kt >> 1, tw = (kt & 1) * 16 + quad * 4;
            for (int dc = 0; dc < 4; dc++) {
                h4 vb = *(const h4*)&Vs[cur][tp][dc * 16 + l16][tw];
                o[dc] = __builtin_amdgcn_mfma_f32_16x16x16f16(pa, vb, o[dc], 0, 0, 0);
            }
        }
        if (more) VSTORE(nxt);
    }
#undef KISSUE
#undef VLOAD
#undef VSTORE

    lsum += __shfl_xor(lsum, 16, 64);
    lsum += __shfl_xor(lsum, 32, 64);
    float rinv = 1.f / lsum;
    float rq[4];
    for (int r = 0; r < 4; r++)
        rq[r] = __shfl(rinv, quad * 4 + r, 64);

    const int b = bh >> 4, h = bh & 15;
    for (int dc = 0; dc < 4; dc++)
        for (int r = 0; r < 4; r++) {
            int q = qrow + quad * 4 + r;
            Hb[((size_t)(b * 2048 + q)) * 1024 + h * 64 + dc * 16 + l16] = f2bf(o[dc][r] * rq[r]);
        }
}

// ---------------- layernorm (row = block), optional bf16 copy ----------------
__global__ __launch_bounds__(256) void ln_kernel(
    float* __restrict__ y, const float* __restrict__ g, const float* __restrict__ be,
    u16* __restrict__ bf_out)
{
    __shared__ float red[8];
    const int row = blockIdx.x, tid = threadIdx.x;
    float4 v = *(const float4*)&y[(size_t)row * 1024 + tid * 4];
    float sum = v.x + v.y + v.z + v.w;
    float sq  = v.x * v.x + v.y * v.y + v.z * v.z + v.w * v.w;
    for (int off = 1; off < 64; off <<= 1) {
        sum += __shfl_xor(sum, off, 64);
        sq  += __shfl_xor(sq,  off, 64);
    }
    int wave = tid >> 6;
    if ((tid & 63) == 0) { red[wave * 2] = sum; red[wave * 2 + 1] = sq; }
    __syncthreads();
    sum = red[0] + red[2] + red[4] + red[6];
    sq  = red[1] + red[3] + red[5] + red[7];
    float mu = sum * (1.f / 1024.f);
    float var = sq * (1.f / 1024.f) - mu * mu;
    float rstd = rsqrtf(var + 1e-5f);
    float4 gv = *(const float4*)&g[tid * 4];
    float4 bv = *(const float4*)&be[tid * 4];
    float4 ov;
    ov.x = (v.x - mu) * rstd * gv.x + bv.x;
    ov.y = (v.y - mu) * rstd * gv.y + bv.y;
    ov.z = (v.z - mu) * rstd * gv.z + bv.z;
    ov.w = (v.w - mu) * rstd * gv.w + bv.w;
    *(float4*)&y[(size_t)row * 1024 + tid * 4] = ov;
    if (bf_out) {
        ushort4 ob;
        ob.x = f2bf(ov.x); ob.y = f2bf(ov.y); ob.z = f2bf(ov.z); ob.w = f2bf(ov.w);
        *(ushort4*)&bf_out[(size_t)row * 1024 + tid * 4] = ob;
    }
}

// ---------------- launch ----------------
extern "C" void kernel_launch(void* const* d_in, const int* in_sizes, int n_in,
                              void* d_out, int out_size, void* d_ws, size_t ws_size,
                              hipStream_t stream)
{
    const float* x     = (const float*)d_in[0];
    const float* Wqkv  = (const float*)d_in[1];
    const float* bqkv  = (const float*)d_in[2];
    const float* Wout  = (const float*)d_in[3];
    const float* bout  = (const float*)d_in[4];
    const float* g1    = (const float*)d_in[5];
    const float* be1   = (const float*)d_in[6];
    const float* Wff1  = (const float*)d_in[7];
    const float* bff1  = (const float*)d_in[8];
    const float* Wff2  = (const float*)d_in[9];
    const float* bff2  = (const float*)d_in[10];
    const float* g2    = (const float*)d_in[11];
    const float* be2   = (const float*)d_in[12];
    float* out = (float*)d_out;

    char* wsb = (char*)d_ws;
    u16* WqkvT = (u16*)(wsb + 0);                   //  6 MB [3072,1024]
    u16* WoutT = (u16*)(wsb + 6291456);             //  2 MB [1024,1024]
    u16* Wff1T = (u16*)(wsb + 8388608);             //  4 MB [2048,1024]
    u16* Wff2T = (u16*)(wsb + 12582912);            //  4 MB [1024,2048]
    u16* xb    = (u16*)(wsb + 16777216);            //  8 MB [4096,1024]; reused as VT
    u16* Qp    = (u16*)(wsb + 25165824);            //  8 MB [B,H,T,D] bf16
    u16* Kp    = (u16*)(wsb + 33554432);            //  8 MB bf16
    u16* Vp    = (u16*)(wsb + 41943040);            //  8 MB f16
    u16* Hb    = (u16*)(wsb + 50331648);            //  8 MB [4096,1024] bf16
    u16* x1b   = (u16*)(wsb + 58720256);            //  8 MB [4096,1024] bf16
    u16* ff1b  = (u16*)(wsb + 67108864);            // 16 MB [4096,2048] bf16
    float* y1  = (float*)(wsb + 83886080);          // 16 MB fp32 [4096,1024]
    u16* VTg   = xb;                                // V^T f16 [bh][d][t]

    // fused weight prep (4 transposes + x convert in 1 launch)
    hipLaunchKernelGGL(prep_weights, dim3(9216), dim3(32, 8), 0, stream,
                       Wqkv, WqkvT, Wout, WoutT, Wff1, Wff1T, Wff2, Wff2T, x, xb);

    // QKV projection (Q pre-scaled by 0.125*log2e; V stored f16)
    hipLaunchKernelGGL((gemm_kernel<0>), dim3(24, 32), dim3(256), 0, stream,
                       xb, WqkvT, bqkv, nullptr, nullptr, 4096, 3072, 1024, Qp, Kp, Vp);
    // V transpose (f16 passthrough; overwrites xb — dead now)
    hipLaunchKernelGGL(vtrans_kernel, dim3(32, 32), dim3(64, 8), 0, stream, Vp, VTg);
    // attention (v10)
    hipLaunchKernelGGL(attn_kernel, dim3(1024), dim3(256), 0, stream, Qp, Kp, VTg, Hb);
    // out projection + residual (x fp32) -> y1 fp32   (64x64 BK=64, 1024 blocks)
    hipLaunchKernelGGL((gemm64x64_kernel<0>), dim3(16, 64), dim3(256), 0, stream,
                       Hb, WoutT, bout, y1, (const void*)x, 4096, 1024, 1024);
    // LN1 in-place on y1, emit bf16 x1b
    hipLaunchKernelGGL(ln_kernel, dim3(4096), dim3(256), 0, stream, y1, g1, be1, x1b);
    // FF1 + relu -> ff1b bf16   (64x128, 1024 blocks)
    hipLaunchKernelGGL((gemm64_kernel<2>), dim3(16, 64), dim3(256), 0, stream,
                       x1b, Wff1T, bff1, (void*)ff1b, nullptr, 4096, 2048, 1024);
    // FF2 + residual (x1b bf16) -> d_out fp32   (64x64 BK=64, 1024 blocks)
    hipLaunchKernelGGL((gemm64x64_kernel<1>), dim3(16, 64), dim3(256), 0, stream,
                       ff1b, Wff2T, bff2, out, (const void*)x1b, 4096, 1024, 2048);
    // LN2 in-place on d_out
    hipLaunchKernelGGL(ln_kernel, dim3(4096), dim3(256), 0, stream, out, g2, be2, (u16*)nullptr);
}